// Round 1
// baseline (2537.715 us; speedup 1.0000x reference)
//
#include <hip/hip_runtime.h>

#define NENT  100000
#define NREL  400
#define EMB   100
#define NF    51
#define FCMP  102
#define OUTC  200
#define NEDGE 500000
#define HALFE 250000
#define BATCH 512
#define POSN  196
#define FCK   39200
#define BN_EPS 1e-5f

// ---- workspace layout (floats). Peak ~204.4 MB. z1 overlays Fa+accIn after x is built.
static constexpr size_t OFF_FA     = 0;          // [NENT][102]
static constexpr size_t OFF_ACCIN  = 10200000;   // [NENT][102]
static constexpr size_t OFF_ACCOUT = 20400000;   // [NENT][102]
static constexpr size_t OFF_Z1     = 0;          // [512][39200] overlay
static constexpr size_t OFF_XBUF   = 30600000;   // [NENT][200]
static constexpr size_t OFF_FB     = 50600000;   // [NREL][102]
static constexpr size_t OFF_FL     = 50640800;   // [102] (+pad)
static constexpr size_t OFF_BIGB   = 50640928;   // [306][200]
static constexpr size_t OFF_R      = 50702128;   // [400][200]
static constexpr size_t OFF_IMG    = 50782128;   // [512][400]
static constexpr size_t OFF_DFTC   = 50986928;   // [100][51]
static constexpr size_t OFF_DFTS   = 50992028;   // [100][51]
static constexpr size_t OFF_Z      = 50997128;   // [512][200]  (memset region starts here)
static constexpr size_t OFF_COLSUM = OFF_Z + 102400;
static constexpr size_t OFF_COLSS  = OFF_COLSUM + 200;
static constexpr size_t OFF_BN1    = OFF_COLSS + 200;   // 2 (+pad to 8)
static constexpr size_t OFF_CHSUM  = OFF_BN1 + 8;
static constexpr size_t OFF_CHSS   = OFF_CHSUM + 200;
static constexpr size_t WS_END     = OFF_CHSS + 200;

// ---------------- DFT twiddle tables ----------------
__global__ void k_tables(float* __restrict__ ws) {
  int i = blockIdx.x * 256 + threadIdx.x;
  if (i >= EMB * NF) return;
  int j = i / NF, f = i - j * NF;
  int m = (j * f) % EMB;
  float ang = (float)m * 0.06283185307179586f;  // 2*pi/100
  ws[OFF_DFTC + i] = cosf(ang);
  ws[OFF_DFTS + i] = sinf(ang);
}

// ---------------- rfft of rows (direct DFT, n=100 -> 51 complex as [re51|im51]) ----------------
__global__ void k_rfft(const float* __restrict__ src, float* __restrict__ dst,
                       const float* __restrict__ dftc, const float* __restrict__ dfts,
                       int nrows) {
  __shared__ float arow[4][EMB];
  int g = threadIdx.x >> 6;
  int lane = threadIdx.x & 63;
  int row = blockIdx.x * 4 + g;
  if (row < nrows) {
    for (int j = lane; j < EMB; j += 64) arow[g][j] = src[(size_t)row * EMB + j];
  }
  __syncthreads();
  if (row < nrows && lane < NF) {
    float re = 0.f, im = 0.f;
    for (int j = 0; j < EMB; ++j) {
      float a = arow[g][j];
      re += a * dftc[j * NF + lane];
      im -= a * dfts[j * NF + lane];
    }
    dst[(size_t)row * FCMP + lane] = re;
    dst[(size_t)row * FCMP + NF + lane] = im;
  }
}

// ---------------- fold irfft + weight + 1/3 into BigB[306][200]: rows 0..101 = L~ (loop), 102..203 = W~in, 204..305 = W~out
__global__ void k_wtilde(const float* __restrict__ in_w, const float* __restrict__ out_w,
                         const float* __restrict__ loop_w, float* __restrict__ ws) {
  int id = blockIdx.x * 256 + threadIdx.x;
  if (id >= NF * OUTC) return;
  int f = id / OUTC, o = id - f * OUTC;
  const float* dftc = ws + OFF_DFTC;
  const float* dfts = ws + OFF_DFTS;
  float ci = 0, si = 0, co = 0, so = 0, cl = 0, sl = 0;
  for (int k = 0; k < EMB; ++k) {
    float c = dftc[k * NF + f], s = dfts[k * NF + f];
    float wi = in_w[k * OUTC + o], wo = out_w[k * OUTC + o], wl = loop_w[k * OUTC + o];
    ci += c * wi; si += s * wi;
    co += c * wo; so += s * wo;
    cl += c * wl; sl += s * wl;
  }
  bool ends = (f == 0) || (f == NF - 1);
  float mult = ends ? 1.0f : 2.0f;
  const float inv3n = 1.0f / (3.0f * (float)EMB);
  float* bigb = ws + OFF_BIGB;
  bigb[(102 + f) * OUTC + o]      = mult * ci * inv3n;
  bigb[(102 + NF + f) * OUTC + o] = ends ? 0.f : (-2.0f * si * inv3n);
  bigb[(204 + f) * OUTC + o]      = mult * co * inv3n;
  bigb[(204 + NF + f) * OUTC + o] = ends ? 0.f : (-2.0f * so * inv3n);
  float wlre = mult * cl * inv3n;
  float wlim = ends ? 0.f : (-2.0f * sl * inv3n);
  float flr = ws[OFF_FL + f], fli = ws[OFF_FL + NF + f];
  bigb[f * OUTC + o]        = flr * wlre + fli * wlim;
  bigb[(NF + f) * OUTC + o] = fli * wlre - flr * wlim;
}

// ---------------- per-edge: accF[dst,half] += norm * conj(Fa[src]) * Fb[type]  (freq domain) ----------------
__global__ void k_edge(const float* __restrict__ fa_t, const float* __restrict__ fb_t,
                       float* __restrict__ accIn, float* __restrict__ accOut,
                       const int* __restrict__ esrc, const int* __restrict__ edst,
                       const int* __restrict__ etyp, const float* __restrict__ enorm) {
  int sub = threadIdx.x >> 7;
  int l = threadIdx.x & 127;
  int e = blockIdx.x * 2 + sub;
  if (e >= NEDGE || l >= FCMP) return;
  int s = esrc[e], d = edst[e], ty = etyp[e];
  float nor = enorm[e];
  int f = (l < NF) ? l : (l - NF);
  const float* fa = fa_t + (size_t)s * FCMP;
  const float* fb = fb_t + (size_t)ty * FCMP;
  float far = fa[f], fai = fa[NF + f], fbr = fb[f], fbi = fb[NF + f];
  float v = (l < NF) ? (far * fbr + fai * fbi) : (far * fbi - fai * fbr);
  float* acc = (e < HALFE) ? accIn : accOut;
  atomicAdd(acc + (size_t)d * FCMP + l, v * nor);
}

// ---------------- r = rel_emb @ w_rel ----------------
__global__ void k_relmat(const float* __restrict__ rel_emb, const float* __restrict__ w_rel,
                         float* __restrict__ r) {
  int id = blockIdx.x * 256 + threadIdx.x;
  if (id >= NREL * OUTC) return;
  int rr = id / OUTC, o = id - rr * OUTC;
  float acc = 0.f;
  for (int k = 0; k < EMB; ++k) acc += rel_emb[rr * EMB + k] * w_rel[k * OUTC + o];
  r[id] = acc;
}

// ---------------- x_pre = [Fa | accIn | accOut] @ BigB   (per block: 32 rows x 200 cols) ----------------
__global__ void __launch_bounds__(256) k_fused_x(const float* __restrict__ ws, float* __restrict__ xbuf) {
  __shared__ float As[32 * 308];
  int t = threadIdx.x;
  size_t n0 = (size_t)blockIdx.x * 32;
  const float* Fa = ws + OFF_FA;
  const float* aI = ws + OFF_ACCIN;
  const float* aO = ws + OFF_ACCOUT;
  for (int idx = t; idx < 32 * 308; idx += 256) {
    int r = idx / 308, k = idx - r * 308;
    size_t n = n0 + r;
    float v = 0.f;
    if (k < 102)      v = Fa[n * FCMP + k];
    else if (k < 204) v = aI[n * FCMP + (k - 102)];
    else if (k < 306) v = aO[n * FCMP + (k - 204)];
    As[r * 308 + k] = v;
  }
  __syncthreads();
  if (t < OUTC) {
    const float* B = ws + OFF_BIGB;
    float acc[32];
    #pragma unroll
    for (int r = 0; r < 32; ++r) acc[r] = 0.f;
    for (int k4 = 0; k4 < 304; k4 += 4) {
      float b0 = B[(size_t)(k4 + 0) * OUTC + t];
      float b1 = B[(size_t)(k4 + 1) * OUTC + t];
      float b2 = B[(size_t)(k4 + 2) * OUTC + t];
      float b3 = B[(size_t)(k4 + 3) * OUTC + t];
      #pragma unroll
      for (int r = 0; r < 32; ++r) {
        float4 a = *(const float4*)&As[r * 308 + k4];
        acc[r] += a.x * b0 + a.y * b1 + a.z * b2 + a.w * b3;
      }
    }
    { // tail k = 304,305
      float b0 = B[(size_t)304 * OUTC + t];
      float b1 = B[(size_t)305 * OUTC + t];
      #pragma unroll
      for (int r = 0; r < 32; ++r) {
        float2 a = *(const float2*)&As[r * 308 + 304];
        acc[r] += a.x * b0 + a.y * b1;
      }
    }
    #pragma unroll 4
    for (int r = 0; r < 32; ++r) xbuf[(n0 + r) * OUTC + t] = acc[r];
  }
}

// ---------------- column stats of xbuf ----------------
__global__ void k_colstats(const float* __restrict__ x, float* __restrict__ colsum,
                           float* __restrict__ colss) {
  int t = threadIdx.x;
  if (t >= OUTC) return;
  size_t r0 = (size_t)blockIdx.x * 500;
  float s1 = 0.f, s2 = 0.f;
  for (int i = 0; i < 500; ++i) {
    float v = x[(r0 + i) * OUTC + t];
    s1 += v; s2 += v * v;
  }
  atomicAdd(colsum + t, s1);
  atomicAdd(colss + t, s2);
}

// ---------------- x = tanh(bn0(x_pre)) in place ----------------
__global__ void k_bn_tanh(float* __restrict__ x, const float* __restrict__ colsum,
                          const float* __restrict__ colss) {
  size_t i = (size_t)blockIdx.x * 256 + threadIdx.x;
  if (i >= 5000000ull) return;  // NENT*OUTC/4
  float4 v = ((float4*)x)[i];
  int c = (int)((i * 4) % OUTC);
  const float inv = 1.0f / (float)NENT;
  float m, q, rs;
  m = colsum[c] * inv;     q = colss[c] * inv - m * m;     rs = rsqrtf(q + BN_EPS); v.x = tanhf((v.x - m) * rs);
  m = colsum[c + 1] * inv; q = colss[c + 1] * inv - m * m; rs = rsqrtf(q + BN_EPS); v.y = tanhf((v.y - m) * rs);
  m = colsum[c + 2] * inv; q = colss[c + 2] * inv - m * m; rs = rsqrtf(q + BN_EPS); v.z = tanhf((v.z - m) * rs);
  m = colsum[c + 3] * inv; q = colss[c + 3] * inv - m * m; rs = rsqrtf(q + BN_EPS); v.w = tanhf((v.w - m) * rs);
  ((float4*)x)[i] = v;
}

// ---------------- gather ConvE input image + global bn stats ----------------
__global__ void k_gather_img(const float* __restrict__ x, const float* __restrict__ r,
                             const int* __restrict__ head, const int* __restrict__ rela,
                             float* __restrict__ img, float* __restrict__ bn1) {
  int b = blockIdx.x, t = threadIdx.x;
  int h = head[b], q = rela[b];
  float s1 = 0.f, s2 = 0.f;
  for (int j = t; j < 400; j += 256) {
    float v = (j < OUTC) ? x[(size_t)h * OUTC + j] : r[(size_t)q * OUTC + (j - OUTC)];
    img[(size_t)b * 400 + j] = v;
    s1 += v; s2 += v * v;
  }
  for (int off = 32; off; off >>= 1) { s1 += __shfl_down(s1, off); s2 += __shfl_down(s2, off); }
  if ((t & 63) == 0) { atomicAdd(bn1, s1); atomicAdd(bn1 + 1, s2); }
}

// ---------------- conv 7x7 valid (1->200 ch) on bn1-normalized 20x20 image + per-channel stats ----------------
__global__ void __launch_bounds__(256) k_conv(const float* __restrict__ img, const float* __restrict__ conv_w,
                                              const float* __restrict__ bn1, float* __restrict__ z1,
                                              float* __restrict__ chsum, float* __restrict__ chss) {
  __shared__ float imgn[400];
  int b = blockIdx.x, t = threadIdx.x;
  float m = bn1[0] * (1.0f / 204800.0f);
  float var = bn1[1] * (1.0f / 204800.0f) - m * m;
  float rs = rsqrtf(var + BN_EPS);
  for (int j = t; j < 400; j += 256) imgn[j] = (img[(size_t)b * 400 + j] - m) * rs;
  __syncthreads();
  if (t < OUTC) {
    float w[49];
    #pragma unroll
    for (int i = 0; i < 49; ++i) w[i] = conv_w[t * 49 + i];
    float s1 = 0.f, s2 = 0.f;
    size_t base = (size_t)b * FCK + (size_t)t * POSN;
    for (int pos = 0; pos < POSN; ++pos) {
      int y = pos / 14, xx = pos - y * 14;
      float acc = 0.f;
      #pragma unroll
      for (int ky = 0; ky < 7; ++ky)
        #pragma unroll
        for (int kx = 0; kx < 7; ++kx)
          acc += imgn[(y + ky) * 20 + xx + kx] * w[ky * 7 + kx];
      z1[base + pos] = acc;
      s1 += acc; s2 += acc * acc;
    }
    atomicAdd(chsum + t, s1);
    atomicAdd(chss + t, s2);
  }
}

// ---------------- z1 = relu(bn2(z1)) in place ----------------
__global__ void k_bn2_relu(float* __restrict__ z1, const float* __restrict__ chsum,
                           const float* __restrict__ chss) {
  size_t i = (size_t)blockIdx.x * 256 + threadIdx.x;
  if (i >= 5017600ull) return;  // 512*39200/4
  float4 v = ((float4*)z1)[i];
  int c = (int)((i * 4 % FCK) / POSN);
  const float inv = 1.0f / (512.0f * 196.0f);
  float m = chsum[c] * inv;
  float var = chss[c] * inv - m * m;
  float rs = rsqrtf(var + BN_EPS);
  v.x = fmaxf((v.x - m) * rs, 0.f);
  v.y = fmaxf((v.y - m) * rs, 0.f);
  v.z = fmaxf((v.z - m) * rs, 0.f);
  v.w = fmaxf((v.w - m) * rs, 0.f);
  ((float4*)z1)[i] = v;
}

// ---------------- fc: z += z1 @ fc_w.T   (K-split 16, atomic epilogue) ----------------
__global__ void __launch_bounds__(256) k_fc(const float* __restrict__ A, const float* __restrict__ Bw,
                                            float* __restrict__ Cz) {
  __shared__ float As[49 * 68];
  __shared__ float Bs[49 * 68];
  int t = threadIdx.x;
  int m0 = blockIdx.x * 64;
  int n0 = blockIdx.y * 64;
  int kz = blockIdx.z * 2450;
  int tm = t >> 4, tn = t & 15;
  float acc[4][4];
  #pragma unroll
  for (int i = 0; i < 4; ++i)
    #pragma unroll
    for (int j = 0; j < 4; ++j) acc[i][j] = 0.f;
  for (int chunk = 0; chunk < 50; ++chunk) {
    int kb = kz + chunk * 49;
    __syncthreads();
    for (int idx = t; idx < 64 * 49; idx += 256) {
      int r = idx / 49, k = idx - r * 49;
      As[k * 68 + r] = A[(size_t)(m0 + r) * FCK + kb + k];
      int col = n0 + r;
      Bs[k * 68 + r] = (col < OUTC) ? Bw[(size_t)col * FCK + kb + k] : 0.f;
    }
    __syncthreads();
    for (int k = 0; k < 49; ++k) {
      float4 a = *(const float4*)&As[k * 68 + tm * 4];
      float4 b = *(const float4*)&Bs[k * 68 + tn * 4];
      float av[4] = {a.x, a.y, a.z, a.w}, bv[4] = {b.x, b.y, b.z, b.w};
      #pragma unroll
      for (int i = 0; i < 4; ++i)
        #pragma unroll
        for (int j = 0; j < 4; ++j) acc[i][j] += av[i] * bv[j];
    }
  }
  #pragma unroll
  for (int i = 0; i < 4; ++i) {
    int row = m0 + tm * 4 + i;
    #pragma unroll
    for (int j = 0; j < 4; ++j) {
      int col = n0 + tn * 4 + j;
      if (col < OUTC) atomicAdd(&Cz[(size_t)row * OUTC + col], acc[i][j]);
    }
  }
}

// ---------------- z = relu(bn3(z)) in place (per-column over 512) ----------------
__global__ void k_bn3_relu(float* __restrict__ z) {
  int c = blockIdx.x, lane = threadIdx.x;  // 64 threads
  float v[8];
  float s1 = 0.f, s2 = 0.f;
  #pragma unroll
  for (int i = 0; i < 8; ++i) {
    v[i] = z[(size_t)(lane + i * 64) * OUTC + c];
    s1 += v[i]; s2 += v[i] * v[i];
  }
  for (int off = 32; off; off >>= 1) { s1 += __shfl_down(s1, off); s2 += __shfl_down(s2, off); }
  s1 = __shfl(s1, 0); s2 = __shfl(s2, 0);
  float m = s1 * (1.0f / 512.0f);
  float var = s2 * (1.0f / 512.0f) - m * m;
  float rs = rsqrtf(var + BN_EPS);
  #pragma unroll
  for (int i = 0; i < 8; ++i)
    z[(size_t)(lane + i * 64) * OUTC + c] = fmaxf((v[i] - m) * rs, 0.f);
}

// ---------------- score = sigmoid(z @ x.T + b_ent) ----------------
__global__ void __launch_bounds__(256) k_score(const float* __restrict__ z, const float* __restrict__ x,
                                               const float* __restrict__ b_ent, float* __restrict__ out) {
  __shared__ float zsT[100 * 68];
  __shared__ float xsT[100 * 68];
  int t = threadIdx.x;
  int e0 = blockIdx.x * 64, m0 = blockIdx.y * 64;
  int tm = t >> 4, tn = t & 15;
  float acc[4][4];
  #pragma unroll
  for (int i = 0; i < 4; ++i)
    #pragma unroll
    for (int j = 0; j < 4; ++j) acc[i][j] = 0.f;
  for (int chunk = 0; chunk < 2; ++chunk) {
    int kc = chunk * 100;
    __syncthreads();
    for (int idx = t; idx < 6400; idx += 256) {
      int r = idx / 100, k = idx - r * 100;
      zsT[k * 68 + r] = z[(size_t)(m0 + r) * OUTC + kc + k];
      int e = e0 + r;
      xsT[k * 68 + r] = (e < NENT) ? x[(size_t)e * OUTC + kc + k] : 0.f;
    }
    __syncthreads();
    for (int k = 0; k < 100; ++k) {
      float4 a = *(const float4*)&zsT[k * 68 + tm * 4];
      float4 b = *(const float4*)&xsT[k * 68 + tn * 4];
      float av[4] = {a.x, a.y, a.z, a.w}, bv[4] = {b.x, b.y, b.z, b.w};
      #pragma unroll
      for (int i = 0; i < 4; ++i)
        #pragma unroll
        for (int j = 0; j < 4; ++j) acc[i][j] += av[i] * bv[j];
    }
  }
  #pragma unroll
  for (int i = 0; i < 4; ++i) {
    size_t row = (size_t)(m0 + tm * 4 + i) * NENT;
    #pragma unroll
    for (int j = 0; j < 4; ++j) {
      int e = e0 + tn * 4 + j;
      if (e < NENT) out[row + e] = 1.0f / (1.0f + expf(-(acc[i][j] + b_ent[e])));
    }
  }
}

extern "C" void kernel_launch(void* const* d_in, const int* in_sizes, int n_in,
                              void* d_out, int out_size, void* d_ws, size_t ws_size,
                              hipStream_t stream) {
  (void)in_sizes; (void)n_in; (void)out_size; (void)ws_size;
  const float* ent_emb  = (const float*)d_in[0];
  const float* rel_emb  = (const float*)d_in[1];
  const float* in_w     = (const float*)d_in[2];
  const float* out_w    = (const float*)d_in[3];
  const float* loop_w   = (const float*)d_in[4];
  const float* w_rel    = (const float*)d_in[5];
  const float* loop_rel = (const float*)d_in[6];
  // d_in[7] gcn_bias: cancels under axis-0 BN
  const float* edge_norm= (const float*)d_in[8];
  const float* conv_w   = (const float*)d_in[9];
  const float* fc_w     = (const float*)d_in[10];
  // d_in[11] fc_b: cancels under axis-0 BN
  const float* b_ent    = (const float*)d_in[12];
  const int* esrc = (const int*)d_in[13];
  const int* edst = (const int*)d_in[14];
  const int* etyp = (const int*)d_in[15];
  const int* head = (const int*)d_in[16];
  const int* rela = (const int*)d_in[17];
  float* ws  = (float*)d_ws;
  float* out = (float*)d_out;

  // zero: acc buffers + (z + all stats)
  hipMemsetAsync(ws + OFF_ACCIN, 0, (size_t)20400000 * 4, stream);
  hipMemsetAsync(ws + OFF_Z, 0, (WS_END - OFF_Z) * 4, stream);

  k_tables<<<20, 256, 0, stream>>>(ws);
  k_rfft<<<25000, 256, 0, stream>>>(ent_emb, ws + OFF_FA, ws + OFF_DFTC, ws + OFF_DFTS, NENT);
  k_rfft<<<100, 256, 0, stream>>>(rel_emb, ws + OFF_FB, ws + OFF_DFTC, ws + OFF_DFTS, NREL);
  k_rfft<<<1, 256, 0, stream>>>(loop_rel, ws + OFF_FL, ws + OFF_DFTC, ws + OFF_DFTS, 1);
  k_wtilde<<<40, 256, 0, stream>>>(in_w, out_w, loop_w, ws);
  k_edge<<<NEDGE / 2, 256, 0, stream>>>(ws + OFF_FA, ws + OFF_FB, ws + OFF_ACCIN, ws + OFF_ACCOUT,
                                        esrc, edst, etyp, edge_norm);
  k_relmat<<<313, 256, 0, stream>>>(rel_emb, w_rel, ws + OFF_R);
  k_fused_x<<<3125, 256, 0, stream>>>(ws, ws + OFF_XBUF);
  k_colstats<<<200, 256, 0, stream>>>(ws + OFF_XBUF, ws + OFF_COLSUM, ws + OFF_COLSS);
  k_bn_tanh<<<19532, 256, 0, stream>>>(ws + OFF_XBUF, ws + OFF_COLSUM, ws + OFF_COLSS);
  k_gather_img<<<512, 256, 0, stream>>>(ws + OFF_XBUF, ws + OFF_R, head, rela, ws + OFF_IMG, ws + OFF_BN1);
  k_conv<<<512, 256, 0, stream>>>(ws + OFF_IMG, conv_w, ws + OFF_BN1, ws + OFF_Z1,
                                  ws + OFF_CHSUM, ws + OFF_CHSS);
  k_bn2_relu<<<19600, 256, 0, stream>>>(ws + OFF_Z1, ws + OFF_CHSUM, ws + OFF_CHSS);
  k_fc<<<dim3(8, 4, 16), 256, 0, stream>>>(ws + OFF_Z1, fc_w, ws + OFF_Z);
  k_bn3_relu<<<200, 64, 0, stream>>>(ws + OFF_Z);
  k_score<<<dim3(1563, 8), 256, 0, stream>>>(ws + OFF_Z, ws + OFF_XBUF, b_ent, out);
}

// Round 2
// 1746.649 us; speedup vs baseline: 1.4529x; 1.4529x over previous
//
#include <hip/hip_runtime.h>

#define NENT  100000
#define NREL  400
#define EMB   100
#define NF    51
#define FCMP  102
#define OUTC  200
#define NEDGE 500000
#define HALFE 250000
#define BATCH 512
#define POSN  196
#define FCK   39200
#define BN_EPS 1e-5f

// ---- workspace layout (floats). Peak ~204 MB (unchanged from R1).
// Lifetimes: Fa dead after k_fused_x -> x_bf overlays it.
//            accIn/accOut dead after k_fused_x -> z1 overlays them.
//            img dead after k_conv -> z_bf overlays it.
static constexpr size_t OFF_FA     = 0;          // [NENT][102]
static constexpr size_t OFF_XBF    = 0;          // [NENT][200] bf16 overlay (10,000,000 floats)
static constexpr size_t OFF_ACCIN  = 10200000;   // [NENT][102]
static constexpr size_t OFF_Z1     = 10200000;   // [512][39200] overlay (20,070,400 floats)
static constexpr size_t OFF_ACCOUT = 20400000;   // [NENT][102]
static constexpr size_t OFF_XBUF   = 30600000;   // [NENT][200] fp32
static constexpr size_t OFF_FB     = 50600000;   // [NREL][102]
static constexpr size_t OFF_FL     = 50640800;   // [102] (+pad)
static constexpr size_t OFF_BIGB   = 50640928;   // [306][200]
static constexpr size_t OFF_R      = 50702128;   // [400][200]
static constexpr size_t OFF_IMG    = 50782128;   // [512][400]
static constexpr size_t OFF_ZBF    = 50782128;   // [512][200] bf16 overlay (25,600 floats)
static constexpr size_t OFF_DFTC   = 50986928;   // [100][51]
static constexpr size_t OFF_DFTS   = 50992028;   // [100][51]
static constexpr size_t OFF_Z      = 50997128;   // [512][200]  (memset region starts here)
static constexpr size_t OFF_COLSUM = OFF_Z + 102400;
static constexpr size_t OFF_COLSS  = OFF_COLSUM + 200;
static constexpr size_t OFF_BN1    = OFF_COLSS + 200;   // 2 (+pad to 8)
static constexpr size_t OFF_CHSUM  = OFF_BN1 + 8;
static constexpr size_t OFF_CHSS   = OFF_CHSUM + 200;
static constexpr size_t WS_END     = OFF_CHSS + 200;

typedef __attribute__((ext_vector_type(8))) short bf16x8;
typedef __attribute__((ext_vector_type(4))) float f32x4;

__device__ inline unsigned short f2bf(float f) {  // RNE float->bf16 bits (no NaN inputs here)
  unsigned int u = __float_as_uint(f);
  unsigned int r = (u + 0x7fffu + ((u >> 16) & 1u)) >> 16;
  return (unsigned short)r;
}

// ---------------- DFT twiddle tables ----------------
__global__ void k_tables(float* __restrict__ ws) {
  int i = blockIdx.x * 256 + threadIdx.x;
  if (i >= EMB * NF) return;
  int j = i / NF, f = i - j * NF;
  int m = (j * f) % EMB;
  float ang = (float)m * 0.06283185307179586f;  // 2*pi/100
  ws[OFF_DFTC + i] = cosf(ang);
  ws[OFF_DFTS + i] = sinf(ang);
}

// ---------------- rfft of rows (direct DFT, n=100 -> 51 complex as [re51|im51]) ----------------
__global__ void k_rfft(const float* __restrict__ src, float* __restrict__ dst,
                       const float* __restrict__ dftc, const float* __restrict__ dfts,
                       int nrows) {
  __shared__ float arow[4][EMB];
  int g = threadIdx.x >> 6;
  int lane = threadIdx.x & 63;
  int row = blockIdx.x * 4 + g;
  if (row < nrows) {
    for (int j = lane; j < EMB; j += 64) arow[g][j] = src[(size_t)row * EMB + j];
  }
  __syncthreads();
  if (row < nrows && lane < NF) {
    float re = 0.f, im = 0.f;
    for (int j = 0; j < EMB; ++j) {
      float a = arow[g][j];
      re += a * dftc[j * NF + lane];
      im -= a * dfts[j * NF + lane];
    }
    dst[(size_t)row * FCMP + lane] = re;
    dst[(size_t)row * FCMP + NF + lane] = im;
  }
}

// ---------------- fold irfft + weight + 1/3 into BigB[306][200] ----------------
__global__ void k_wtilde(const float* __restrict__ in_w, const float* __restrict__ out_w,
                         const float* __restrict__ loop_w, float* __restrict__ ws) {
  int id = blockIdx.x * 256 + threadIdx.x;
  if (id >= NF * OUTC) return;
  int f = id / OUTC, o = id - f * OUTC;
  const float* dftc = ws + OFF_DFTC;
  const float* dfts = ws + OFF_DFTS;
  float ci = 0, si = 0, co = 0, so = 0, cl = 0, sl = 0;
  for (int k = 0; k < EMB; ++k) {
    float c = dftc[k * NF + f], s = dfts[k * NF + f];
    float wi = in_w[k * OUTC + o], wo = out_w[k * OUTC + o], wl = loop_w[k * OUTC + o];
    ci += c * wi; si += s * wi;
    co += c * wo; so += s * wo;
    cl += c * wl; sl += s * wl;
  }
  bool ends = (f == 0) || (f == NF - 1);
  float mult = ends ? 1.0f : 2.0f;
  const float inv3n = 1.0f / (3.0f * (float)EMB);
  float* bigb = ws + OFF_BIGB;
  bigb[(102 + f) * OUTC + o]      = mult * ci * inv3n;
  bigb[(102 + NF + f) * OUTC + o] = ends ? 0.f : (-2.0f * si * inv3n);
  bigb[(204 + f) * OUTC + o]      = mult * co * inv3n;
  bigb[(204 + NF + f) * OUTC + o] = ends ? 0.f : (-2.0f * so * inv3n);
  float wlre = mult * cl * inv3n;
  float wlim = ends ? 0.f : (-2.0f * sl * inv3n);
  float flr = ws[OFF_FL + f], fli = ws[OFF_FL + NF + f];
  bigb[f * OUTC + o]        = flr * wlre + fli * wlim;
  bigb[(NF + f) * OUTC + o] = fli * wlre - flr * wlim;
}

// ---------------- per-edge: accF[dst,half] += norm * conj(Fa[src]) * Fb[type] ----------------
__global__ void k_edge(const float* __restrict__ fa_t, const float* __restrict__ fb_t,
                       float* __restrict__ accIn, float* __restrict__ accOut,
                       const int* __restrict__ esrc, const int* __restrict__ edst,
                       const int* __restrict__ etyp, const float* __restrict__ enorm) {
  int sub = threadIdx.x >> 7;
  int l = threadIdx.x & 127;
  int e = blockIdx.x * 2 + sub;
  if (e >= NEDGE || l >= FCMP) return;
  int s = esrc[e], d = edst[e], ty = etyp[e];
  float nor = enorm[e];
  int f = (l < NF) ? l : (l - NF);
  const float* fa = fa_t + (size_t)s * FCMP;
  const float* fb = fb_t + (size_t)ty * FCMP;
  float far = fa[f], fai = fa[NF + f], fbr = fb[f], fbi = fb[NF + f];
  float v = (l < NF) ? (far * fbr + fai * fbi) : (far * fbi - fai * fbr);
  float* acc = (e < HALFE) ? accIn : accOut;
  atomicAdd(acc + (size_t)d * FCMP + l, v * nor);
}

// ---------------- r = rel_emb @ w_rel ----------------
__global__ void k_relmat(const float* __restrict__ rel_emb, const float* __restrict__ w_rel,
                         float* __restrict__ r) {
  int id = blockIdx.x * 256 + threadIdx.x;
  if (id >= NREL * OUTC) return;
  int rr = id / OUTC, o = id - rr * OUTC;
  float acc = 0.f;
  for (int k = 0; k < EMB; ++k) acc += rel_emb[rr * EMB + k] * w_rel[k * OUTC + o];
  r[id] = acc;
}

// ---------------- x_pre = [Fa | accIn | accOut] @ BigB ----------------
__global__ void __launch_bounds__(256) k_fused_x(const float* __restrict__ ws, float* __restrict__ xbuf) {
  __shared__ float As[32 * 308];
  int t = threadIdx.x;
  size_t n0 = (size_t)blockIdx.x * 32;
  const float* Fa = ws + OFF_FA;
  const float* aI = ws + OFF_ACCIN;
  const float* aO = ws + OFF_ACCOUT;
  for (int idx = t; idx < 32 * 308; idx += 256) {
    int r = idx / 308, k = idx - r * 308;
    size_t n = n0 + r;
    float v = 0.f;
    if (k < 102)      v = Fa[n * FCMP + k];
    else if (k < 204) v = aI[n * FCMP + (k - 102)];
    else if (k < 306) v = aO[n * FCMP + (k - 204)];
    As[r * 308 + k] = v;
  }
  __syncthreads();
  if (t < OUTC) {
    const float* B = ws + OFF_BIGB;
    float acc[32];
    #pragma unroll
    for (int r = 0; r < 32; ++r) acc[r] = 0.f;
    for (int k4 = 0; k4 < 304; k4 += 4) {
      float b0 = B[(size_t)(k4 + 0) * OUTC + t];
      float b1 = B[(size_t)(k4 + 1) * OUTC + t];
      float b2 = B[(size_t)(k4 + 2) * OUTC + t];
      float b3 = B[(size_t)(k4 + 3) * OUTC + t];
      #pragma unroll
      for (int r = 0; r < 32; ++r) {
        float4 a = *(const float4*)&As[r * 308 + k4];
        acc[r] += a.x * b0 + a.y * b1 + a.z * b2 + a.w * b3;
      }
    }
    {
      float b0 = B[(size_t)304 * OUTC + t];
      float b1 = B[(size_t)305 * OUTC + t];
      #pragma unroll
      for (int r = 0; r < 32; ++r) {
        float2 a = *(const float2*)&As[r * 308 + 304];
        acc[r] += a.x * b0 + a.y * b1;
      }
    }
    #pragma unroll 4
    for (int r = 0; r < 32; ++r) xbuf[(n0 + r) * OUTC + t] = acc[r];
  }
}

// ---------------- column stats of xbuf ----------------
__global__ void k_colstats(const float* __restrict__ x, float* __restrict__ colsum,
                           float* __restrict__ colss) {
  int t = threadIdx.x;
  if (t >= OUTC) return;
  size_t r0 = (size_t)blockIdx.x * 500;
  float s1 = 0.f, s2 = 0.f;
  for (int i = 0; i < 500; ++i) {
    float v = x[(r0 + i) * OUTC + t];
    s1 += v; s2 += v * v;
  }
  atomicAdd(colsum + t, s1);
  atomicAdd(colss + t, s2);
}

// ---------------- x = tanh(bn0(x_pre)) in place + bf16 copy ----------------
__global__ void k_bn_tanh(float* __restrict__ x, unsigned short* __restrict__ xb,
                          const float* __restrict__ colsum, const float* __restrict__ colss) {
  size_t i = (size_t)blockIdx.x * 256 + threadIdx.x;
  if (i >= 5000000ull) return;  // NENT*OUTC/4
  float4 v = ((float4*)x)[i];
  int c = (int)((i * 4) % OUTC);
  const float inv = 1.0f / (float)NENT;
  float m, q, rs;
  m = colsum[c] * inv;     q = colss[c] * inv - m * m;     rs = rsqrtf(q + BN_EPS); v.x = tanhf((v.x - m) * rs);
  m = colsum[c + 1] * inv; q = colss[c + 1] * inv - m * m; rs = rsqrtf(q + BN_EPS); v.y = tanhf((v.y - m) * rs);
  m = colsum[c + 2] * inv; q = colss[c + 2] * inv - m * m; rs = rsqrtf(q + BN_EPS); v.z = tanhf((v.z - m) * rs);
  m = colsum[c + 3] * inv; q = colss[c + 3] * inv - m * m; rs = rsqrtf(q + BN_EPS); v.w = tanhf((v.w - m) * rs);
  ((float4*)x)[i] = v;
  ushort4 b;
  b.x = f2bf(v.x); b.y = f2bf(v.y); b.z = f2bf(v.z); b.w = f2bf(v.w);
  *(ushort4*)(xb + i * 4) = b;
}

// ---------------- gather ConvE input image + global bn stats ----------------
__global__ void k_gather_img(const float* __restrict__ x, const float* __restrict__ r,
                             const int* __restrict__ head, const int* __restrict__ rela,
                             float* __restrict__ img, float* __restrict__ bn1) {
  int b = blockIdx.x, t = threadIdx.x;
  int h = head[b], q = rela[b];
  float s1 = 0.f, s2 = 0.f;
  for (int j = t; j < 400; j += 256) {
    float v = (j < OUTC) ? x[(size_t)h * OUTC + j] : r[(size_t)q * OUTC + (j - OUTC)];
    img[(size_t)b * 400 + j] = v;
    s1 += v; s2 += v * v;
  }
  for (int off = 32; off; off >>= 1) { s1 += __shfl_down(s1, off); s2 += __shfl_down(s2, off); }
  if ((t & 63) == 0) { atomicAdd(bn1, s1); atomicAdd(bn1 + 1, s2); }
}

// ---------------- conv 7x7 valid (1->200 ch) + per-channel stats ----------------
__global__ void __launch_bounds__(256) k_conv(const float* __restrict__ img, const float* __restrict__ conv_w,
                                              const float* __restrict__ bn1, float* __restrict__ z1,
                                              float* __restrict__ chsum, float* __restrict__ chss) {
  __shared__ float imgn[400];
  int b = blockIdx.x, t = threadIdx.x;
  float m = bn1[0] * (1.0f / 204800.0f);
  float var = bn1[1] * (1.0f / 204800.0f) - m * m;
  float rs = rsqrtf(var + BN_EPS);
  for (int j = t; j < 400; j += 256) imgn[j] = (img[(size_t)b * 400 + j] - m) * rs;
  __syncthreads();
  if (t < OUTC) {
    float w[49];
    #pragma unroll
    for (int i = 0; i < 49; ++i) w[i] = conv_w[t * 49 + i];
    float s1 = 0.f, s2 = 0.f;
    size_t base = (size_t)b * FCK + (size_t)t * POSN;
    for (int pos = 0; pos < POSN; ++pos) {
      int y = pos / 14, xx = pos - y * 14;
      float acc = 0.f;
      #pragma unroll
      for (int ky = 0; ky < 7; ++ky)
        #pragma unroll
        for (int kx = 0; kx < 7; ++kx)
          acc += imgn[(y + ky) * 20 + xx + kx] * w[ky * 7 + kx];
      z1[base + pos] = acc;
      s1 += acc; s2 += acc * acc;
    }
    atomicAdd(chsum + t, s1);
    atomicAdd(chss + t, s2);
  }
}

// ---------------- z1 = relu(bn2(z1)) in place ----------------
__global__ void k_bn2_relu(float* __restrict__ z1, const float* __restrict__ chsum,
                           const float* __restrict__ chss) {
  size_t i = (size_t)blockIdx.x * 256 + threadIdx.x;
  if (i >= 5017600ull) return;  // 512*39200/4
  float4 v = ((float4*)z1)[i];
  int c = (int)((i * 4 % FCK) / POSN);
  const float inv = 1.0f / (512.0f * 196.0f);
  float m = chsum[c] * inv;
  float var = chss[c] * inv - m * m;
  float rs = rsqrtf(var + BN_EPS);
  v.x = fmaxf((v.x - m) * rs, 0.f);
  v.y = fmaxf((v.y - m) * rs, 0.f);
  v.z = fmaxf((v.z - m) * rs, 0.f);
  v.w = fmaxf((v.w - m) * rs, 0.f);
  ((float4*)z1)[i] = v;
}

// ---------------- fc: z += z1 @ fc_w.T   (K-split 16, atomic epilogue) ----------------
__global__ void __launch_bounds__(256) k_fc(const float* __restrict__ A, const float* __restrict__ Bw,
                                            float* __restrict__ Cz) {
  __shared__ float As[49 * 68];
  __shared__ float Bs[49 * 68];
  int t = threadIdx.x;
  int m0 = blockIdx.x * 64;
  int n0 = blockIdx.y * 64;
  int kz = blockIdx.z * 2450;
  int tm = t >> 4, tn = t & 15;
  float acc[4][4];
  #pragma unroll
  for (int i = 0; i < 4; ++i)
    #pragma unroll
    for (int j = 0; j < 4; ++j) acc[i][j] = 0.f;
  for (int chunk = 0; chunk < 50; ++chunk) {
    int kb = kz + chunk * 49;
    __syncthreads();
    for (int idx = t; idx < 64 * 49; idx += 256) {
      int r = idx / 49, k = idx - r * 49;
      As[k * 68 + r] = A[(size_t)(m0 + r) * FCK + kb + k];
      int col = n0 + r;
      Bs[k * 68 + r] = (col < OUTC) ? Bw[(size_t)col * FCK + kb + k] : 0.f;
    }
    __syncthreads();
    for (int k = 0; k < 49; ++k) {
      float4 a = *(const float4*)&As[k * 68 + tm * 4];
      float4 b = *(const float4*)&Bs[k * 68 + tn * 4];
      float av[4] = {a.x, a.y, a.z, a.w}, bv[4] = {b.x, b.y, b.z, b.w};
      #pragma unroll
      for (int i = 0; i < 4; ++i)
        #pragma unroll
        for (int j = 0; j < 4; ++j) acc[i][j] += av[i] * bv[j];
    }
  }
  #pragma unroll
  for (int i = 0; i < 4; ++i) {
    int row = m0 + tm * 4 + i;
    #pragma unroll
    for (int j = 0; j < 4; ++j) {
      int col = n0 + tn * 4 + j;
      if (col < OUTC) atomicAdd(&Cz[(size_t)row * OUTC + col], acc[i][j]);
    }
  }
}

// ---------------- z = relu(bn3(z)) -> bf16 z_bf (per-column over 512) ----------------
__global__ void k_bn3_relu(const float* __restrict__ z, unsigned short* __restrict__ zb) {
  int c = blockIdx.x, lane = threadIdx.x;  // 64 threads
  float v[8];
  float s1 = 0.f, s2 = 0.f;
  #pragma unroll
  for (int i = 0; i < 8; ++i) {
    v[i] = z[(size_t)(lane + i * 64) * OUTC + c];
    s1 += v[i]; s2 += v[i] * v[i];
  }
  for (int off = 32; off; off >>= 1) { s1 += __shfl_down(s1, off); s2 += __shfl_down(s2, off); }
  s1 = __shfl(s1, 0); s2 = __shfl(s2, 0);
  float m = s1 * (1.0f / 512.0f);
  float var = s2 * (1.0f / 512.0f) - m * m;
  float rs = rsqrtf(var + BN_EPS);
  #pragma unroll
  for (int i = 0; i < 8; ++i)
    zb[(size_t)(lane + i * 64) * OUTC + c] = f2bf(fmaxf((v[i] - m) * rs, 0.f));
}

// ---------------- score = sigmoid(z_bf @ x_bf.T + b_ent) via MFMA ----------------
// A = z_bf [512][200] bf16, B = x_bf [100000][200] bf16 (gemm_bt pattern).
// Block: 4 waves; wave w computes rows [by*128+w*32, +32) x cols [bx*128, +128).
// K = 6 full 16x16x32 steps + 1 masked step (k=192..199 live only for kg==0).
__global__ void __launch_bounds__(256) k_score_mfma(const unsigned short* __restrict__ zb,
                                                    const unsigned short* __restrict__ xb,
                                                    const float* __restrict__ b_ent,
                                                    float* __restrict__ out) {
  int t = threadIdx.x;
  int w = t >> 6, l = t & 63;
  int lr = l & 15, kg = l >> 4;
  int m0 = blockIdx.y * 128 + w * 32;
  int e0 = blockIdx.x * 128;
  f32x4 acc[2][8];
  #pragma unroll
  for (int i = 0; i < 2; ++i)
    #pragma unroll
    for (int j = 0; j < 8; ++j) acc[i][j] = (f32x4){0.f, 0.f, 0.f, 0.f};

  #pragma unroll
  for (int step = 0; step < 7; ++step) {
    int k = step * 32 + kg * 8;
    bool valid = (k < 200);  // steps 0..5 always true; step 6 only kg==0
    bf16x8 a[2], b[8];
    #pragma unroll
    for (int i = 0; i < 2; ++i) {
      int row = m0 + i * 16 + lr;
      a[i] = valid ? *(const bf16x8*)(zb + (size_t)row * OUTC + k) : (bf16x8)0;
    }
    #pragma unroll
    for (int j = 0; j < 8; ++j) {
      int col = e0 + j * 16 + lr;  // cols >= NENT read in-ws garbage; masked on write
      b[j] = valid ? *(const bf16x8*)(xb + (size_t)col * OUTC + k) : (bf16x8)0;
    }
    #pragma unroll
    for (int i = 0; i < 2; ++i)
      #pragma unroll
      for (int j = 0; j < 8; ++j)
        acc[i][j] = __builtin_amdgcn_mfma_f32_16x16x32_bf16(a[i], b[j], acc[i][j], 0, 0, 0);
  }

  #pragma unroll
  for (int i = 0; i < 2; ++i) {
    #pragma unroll
    for (int j = 0; j < 8; ++j) {
      int e = e0 + j * 16 + lr;
      if (e < NENT) {
        float be = b_ent[e];
        #pragma unroll
        for (int r = 0; r < 4; ++r) {
          int row = m0 + i * 16 + kg * 4 + r;
          float v = acc[i][j][r] + be;
          out[(size_t)row * NENT + e] = 1.0f / (1.0f + expf(-v));
        }
      }
    }
  }
}

extern "C" void kernel_launch(void* const* d_in, const int* in_sizes, int n_in,
                              void* d_out, int out_size, void* d_ws, size_t ws_size,
                              hipStream_t stream) {
  (void)in_sizes; (void)n_in; (void)out_size; (void)ws_size;
  const float* ent_emb  = (const float*)d_in[0];
  const float* rel_emb  = (const float*)d_in[1];
  const float* in_w     = (const float*)d_in[2];
  const float* out_w    = (const float*)d_in[3];
  const float* loop_w   = (const float*)d_in[4];
  const float* w_rel    = (const float*)d_in[5];
  const float* loop_rel = (const float*)d_in[6];
  // d_in[7] gcn_bias: cancels under axis-0 BN
  const float* edge_norm= (const float*)d_in[8];
  const float* conv_w   = (const float*)d_in[9];
  const float* fc_w     = (const float*)d_in[10];
  // d_in[11] fc_b: cancels under axis-0 BN
  const float* b_ent    = (const float*)d_in[12];
  const int* esrc = (const int*)d_in[13];
  const int* edst = (const int*)d_in[14];
  const int* etyp = (const int*)d_in[15];
  const int* head = (const int*)d_in[16];
  const int* rela = (const int*)d_in[17];
  float* ws  = (float*)d_ws;
  float* out = (float*)d_out;

  // zero: acc buffers + (z + all stats)
  hipMemsetAsync(ws + OFF_ACCIN, 0, (size_t)20400000 * 4, stream);
  hipMemsetAsync(ws + OFF_Z, 0, (WS_END - OFF_Z) * 4, stream);

  k_tables<<<20, 256, 0, stream>>>(ws);
  k_rfft<<<25000, 256, 0, stream>>>(ent_emb, ws + OFF_FA, ws + OFF_DFTC, ws + OFF_DFTS, NENT);
  k_rfft<<<100, 256, 0, stream>>>(rel_emb, ws + OFF_FB, ws + OFF_DFTC, ws + OFF_DFTS, NREL);
  k_rfft<<<1, 256, 0, stream>>>(loop_rel, ws + OFF_FL, ws + OFF_DFTC, ws + OFF_DFTS, 1);
  k_wtilde<<<40, 256, 0, stream>>>(in_w, out_w, loop_w, ws);
  k_edge<<<NEDGE / 2, 256, 0, stream>>>(ws + OFF_FA, ws + OFF_FB, ws + OFF_ACCIN, ws + OFF_ACCOUT,
                                        esrc, edst, etyp, edge_norm);
  k_relmat<<<313, 256, 0, stream>>>(rel_emb, w_rel, ws + OFF_R);
  k_fused_x<<<3125, 256, 0, stream>>>(ws, ws + OFF_XBUF);
  k_colstats<<<200, 256, 0, stream>>>(ws + OFF_XBUF, ws + OFF_COLSUM, ws + OFF_COLSS);
  k_bn_tanh<<<19532, 256, 0, stream>>>(ws + OFF_XBUF, (unsigned short*)(ws + OFF_XBF),
                                       ws + OFF_COLSUM, ws + OFF_COLSS);
  k_gather_img<<<512, 256, 0, stream>>>(ws + OFF_XBUF, ws + OFF_R, head, rela, ws + OFF_IMG, ws + OFF_BN1);
  k_conv<<<512, 256, 0, stream>>>(ws + OFF_IMG, conv_w, ws + OFF_BN1, ws + OFF_Z1,
                                  ws + OFF_CHSUM, ws + OFF_CHSS);
  k_bn2_relu<<<19600, 256, 0, stream>>>(ws + OFF_Z1, ws + OFF_CHSUM, ws + OFF_CHSS);
  k_fc<<<dim3(8, 4, 16), 256, 0, stream>>>(ws + OFF_Z1, fc_w, ws + OFF_Z);
  k_bn3_relu<<<200, 64, 0, stream>>>(ws + OFF_Z, (unsigned short*)(ws + OFF_ZBF));
  k_score_mfma<<<dim3(782, 4), 256, 0, stream>>>((const unsigned short*)(ws + OFF_ZBF),
                                                 (const unsigned short*)(ws + OFF_XBF),
                                                 b_ent, out);
}

// Round 3
// 1312.819 us; speedup vs baseline: 1.9330x; 1.3305x over previous
//
#include <hip/hip_runtime.h>

#define NENT  100000
#define NREL  400
#define EMB   100
#define NF    51
#define FCMP  102
#define OUTC  200
#define NEDGE 500000
#define HALFE 250000
#define BATCH 512
#define POSN  196
#define FCK   39200
#define BN_EPS 1e-5f

// ---- workspace layout (floats). Peak ~204 MB (unchanged).
// Lifetimes: Fa dead after k_fused_x -> x_h overlays it.
//            accIn dead after k_fused_x -> z1h (f16) overlays it.
//            accOut dead after k_fused_x -> fcw_h (f16) overlays it.
//            img dead after k_conv -> z_h overlays it.
static constexpr size_t OFF_FA     = 0;          // [NENT][102] fp32
static constexpr size_t OFF_XH     = 0;          // [NENT][200] f16 overlay (10,000,000 floats)
static constexpr size_t OFF_ACCIN  = 10200000;   // [NENT][102]
static constexpr size_t OFF_Z1H    = 10200000;   // [512][39200] f16 overlay (10,035,200 floats)
static constexpr size_t OFF_ACCOUT = 20400000;   // [NENT][102]
static constexpr size_t OFF_FCWH   = 20400000;   // [200][39200] f16 overlay (3,920,000 floats)
static constexpr size_t OFF_XBUF   = 30600000;   // [NENT][200] fp32
static constexpr size_t OFF_FB     = 50600000;   // [NREL][102]
static constexpr size_t OFF_FL     = 50640800;   // [102] (+pad)
static constexpr size_t OFF_BIGB   = 50640928;   // [306][200]
static constexpr size_t OFF_R      = 50702128;   // [400][200]
static constexpr size_t OFF_IMG    = 50782128;   // [512][400]
static constexpr size_t OFF_ZH     = 50782128;   // [512][200] f16 overlay
static constexpr size_t OFF_DFTC   = 50986928;   // [100][51]
static constexpr size_t OFF_DFTS   = 50992028;   // [100][51]
static constexpr size_t OFF_Z      = 50997128;   // [512][200]  (memset region starts here)
static constexpr size_t OFF_COLSUM = OFF_Z + 102400;
static constexpr size_t OFF_COLSS  = OFF_COLSUM + 200;
static constexpr size_t OFF_BN1    = OFF_COLSS + 200;   // 2 (+pad to 8)
static constexpr size_t OFF_CHSUM  = OFF_BN1 + 8;
static constexpr size_t OFF_CHSS   = OFF_CHSUM + 200;
static constexpr size_t WS_END     = OFF_CHSS + 200;

typedef __attribute__((ext_vector_type(8))) _Float16 f16x8;
typedef __attribute__((ext_vector_type(4))) _Float16 f16x4;
typedef __attribute__((ext_vector_type(4))) float f32x4;

// ---------------- DFT twiddle tables ----------------
__global__ void k_tables(float* __restrict__ ws) {
  int i = blockIdx.x * 256 + threadIdx.x;
  if (i >= EMB * NF) return;
  int j = i / NF, f = i - j * NF;
  int m = (j * f) % EMB;
  float ang = (float)m * 0.06283185307179586f;  // 2*pi/100
  ws[OFF_DFTC + i] = cosf(ang);
  ws[OFF_DFTS + i] = sinf(ang);
}

// ---------------- rfft of rows (direct DFT, n=100 -> 51 complex as [re51|im51]) ----------------
__global__ void k_rfft(const float* __restrict__ src, float* __restrict__ dst,
                       const float* __restrict__ dftc, const float* __restrict__ dfts,
                       int nrows) {
  __shared__ float arow[4][EMB];
  int g = threadIdx.x >> 6;
  int lane = threadIdx.x & 63;
  int row = blockIdx.x * 4 + g;
  if (row < nrows) {
    for (int j = lane; j < EMB; j += 64) arow[g][j] = src[(size_t)row * EMB + j];
  }
  __syncthreads();
  if (row < nrows && lane < NF) {
    float re = 0.f, im = 0.f;
    for (int j = 0; j < EMB; ++j) {
      float a = arow[g][j];
      re += a * dftc[j * NF + lane];
      im -= a * dfts[j * NF + lane];
    }
    dst[(size_t)row * FCMP + lane] = re;
    dst[(size_t)row * FCMP + NF + lane] = im;
  }
}

// ---------------- fold irfft + weight + 1/3 into BigB[306][200] ----------------
__global__ void k_wtilde(const float* __restrict__ in_w, const float* __restrict__ out_w,
                         const float* __restrict__ loop_w, float* __restrict__ ws) {
  int id = blockIdx.x * 256 + threadIdx.x;
  if (id >= NF * OUTC) return;
  int f = id / OUTC, o = id - f * OUTC;
  const float* dftc = ws + OFF_DFTC;
  const float* dfts = ws + OFF_DFTS;
  float ci = 0, si = 0, co = 0, so = 0, cl = 0, sl = 0;
  for (int k = 0; k < EMB; ++k) {
    float c = dftc[k * NF + f], s = dfts[k * NF + f];
    float wi = in_w[k * OUTC + o], wo = out_w[k * OUTC + o], wl = loop_w[k * OUTC + o];
    ci += c * wi; si += s * wi;
    co += c * wo; so += s * wo;
    cl += c * wl; sl += s * wl;
  }
  bool ends = (f == 0) || (f == NF - 1);
  float mult = ends ? 1.0f : 2.0f;
  const float inv3n = 1.0f / (3.0f * (float)EMB);
  float* bigb = ws + OFF_BIGB;
  bigb[(102 + f) * OUTC + o]      = mult * ci * inv3n;
  bigb[(102 + NF + f) * OUTC + o] = ends ? 0.f : (-2.0f * si * inv3n);
  bigb[(204 + f) * OUTC + o]      = mult * co * inv3n;
  bigb[(204 + NF + f) * OUTC + o] = ends ? 0.f : (-2.0f * so * inv3n);
  float wlre = mult * cl * inv3n;
  float wlim = ends ? 0.f : (-2.0f * sl * inv3n);
  float flr = ws[OFF_FL + f], fli = ws[OFF_FL + NF + f];
  bigb[f * OUTC + o]        = flr * wlre + fli * wlim;
  bigb[(NF + f) * OUTC + o] = fli * wlre - flr * wlim;
}

// ---------------- per-edge: accF[dst,half] += norm * conj(Fa[src]) * Fb[type] ----------------
__global__ void k_edge(const float* __restrict__ fa_t, const float* __restrict__ fb_t,
                       float* __restrict__ accIn, float* __restrict__ accOut,
                       const int* __restrict__ esrc, const int* __restrict__ edst,
                       const int* __restrict__ etyp, const float* __restrict__ enorm) {
  int sub = threadIdx.x >> 7;
  int l = threadIdx.x & 127;
  int e = blockIdx.x * 2 + sub;
  if (e >= NEDGE || l >= FCMP) return;
  int s = esrc[e], d = edst[e], ty = etyp[e];
  float nor = enorm[e];
  int f = (l < NF) ? l : (l - NF);
  const float* fa = fa_t + (size_t)s * FCMP;
  const float* fb = fb_t + (size_t)ty * FCMP;
  float far = fa[f], fai = fa[NF + f], fbr = fb[f], fbi = fb[NF + f];
  float v = (l < NF) ? (far * fbr + fai * fbi) : (far * fbi - fai * fbr);
  float* acc = (e < HALFE) ? accIn : accOut;
  atomicAdd(acc + (size_t)d * FCMP + l, v * nor);
}

// ---------------- r = rel_emb @ w_rel ----------------
__global__ void k_relmat(const float* __restrict__ rel_emb, const float* __restrict__ w_rel,
                         float* __restrict__ r) {
  int id = blockIdx.x * 256 + threadIdx.x;
  if (id >= NREL * OUTC) return;
  int rr = id / OUTC, o = id - rr * OUTC;
  float acc = 0.f;
  for (int k = 0; k < EMB; ++k) acc += rel_emb[rr * EMB + k] * w_rel[k * OUTC + o];
  r[id] = acc;
}

// ---------------- x_pre = [Fa | accIn | accOut] @ BigB ----------------
__global__ void __launch_bounds__(256) k_fused_x(const float* __restrict__ ws, float* __restrict__ xbuf) {
  __shared__ float As[32 * 308];
  int t = threadIdx.x;
  size_t n0 = (size_t)blockIdx.x * 32;
  const float* Fa = ws + OFF_FA;
  const float* aI = ws + OFF_ACCIN;
  const float* aO = ws + OFF_ACCOUT;
  for (int idx = t; idx < 32 * 308; idx += 256) {
    int r = idx / 308, k = idx - r * 308;
    size_t n = n0 + r;
    float v = 0.f;
    if (k < 102)      v = Fa[n * FCMP + k];
    else if (k < 204) v = aI[n * FCMP + (k - 102)];
    else if (k < 306) v = aO[n * FCMP + (k - 204)];
    As[r * 308 + k] = v;
  }
  __syncthreads();
  if (t < OUTC) {
    const float* B = ws + OFF_BIGB;
    float acc[32];
    #pragma unroll
    for (int r = 0; r < 32; ++r) acc[r] = 0.f;
    for (int k4 = 0; k4 < 304; k4 += 4) {
      float b0 = B[(size_t)(k4 + 0) * OUTC + t];
      float b1 = B[(size_t)(k4 + 1) * OUTC + t];
      float b2 = B[(size_t)(k4 + 2) * OUTC + t];
      float b3 = B[(size_t)(k4 + 3) * OUTC + t];
      #pragma unroll
      for (int r = 0; r < 32; ++r) {
        float4 a = *(const float4*)&As[r * 308 + k4];
        acc[r] += a.x * b0 + a.y * b1 + a.z * b2 + a.w * b3;
      }
    }
    {
      float b0 = B[(size_t)304 * OUTC + t];
      float b1 = B[(size_t)305 * OUTC + t];
      #pragma unroll
      for (int r = 0; r < 32; ++r) {
        float2 a = *(const float2*)&As[r * 308 + 304];
        acc[r] += a.x * b0 + a.y * b1;
      }
    }
    #pragma unroll 4
    for (int r = 0; r < 32; ++r) xbuf[(n0 + r) * OUTC + t] = acc[r];
  }
}

// ---------------- column stats of xbuf ----------------
__global__ void k_colstats(const float* __restrict__ x, float* __restrict__ colsum,
                           float* __restrict__ colss) {
  int t = threadIdx.x;
  if (t >= OUTC) return;
  size_t r0 = (size_t)blockIdx.x * 500;
  float s1 = 0.f, s2 = 0.f;
  for (int i = 0; i < 500; ++i) {
    float v = x[(r0 + i) * OUTC + t];
    s1 += v; s2 += v * v;
  }
  atomicAdd(colsum + t, s1);
  atomicAdd(colss + t, s2);
}

// ---------------- x = tanh(bn0(x_pre)) in place + f16 copy ----------------
__global__ void k_bn_tanh(float* __restrict__ x, _Float16* __restrict__ xh,
                          const float* __restrict__ colsum, const float* __restrict__ colss) {
  size_t i = (size_t)blockIdx.x * 256 + threadIdx.x;
  if (i >= 5000000ull) return;  // NENT*OUTC/4
  float4 v = ((float4*)x)[i];
  int c = (int)((i * 4) % OUTC);
  const float inv = 1.0f / (float)NENT;
  float m, q, rs;
  m = colsum[c] * inv;     q = colss[c] * inv - m * m;     rs = rsqrtf(q + BN_EPS); v.x = tanhf((v.x - m) * rs);
  m = colsum[c + 1] * inv; q = colss[c + 1] * inv - m * m; rs = rsqrtf(q + BN_EPS); v.y = tanhf((v.y - m) * rs);
  m = colsum[c + 2] * inv; q = colss[c + 2] * inv - m * m; rs = rsqrtf(q + BN_EPS); v.z = tanhf((v.z - m) * rs);
  m = colsum[c + 3] * inv; q = colss[c + 3] * inv - m * m; rs = rsqrtf(q + BN_EPS); v.w = tanhf((v.w - m) * rs);
  ((float4*)x)[i] = v;
  f16x4 h;
  h[0] = (_Float16)v.x; h[1] = (_Float16)v.y; h[2] = (_Float16)v.z; h[3] = (_Float16)v.w;
  *(f16x4*)(xh + i * 4) = h;
}

// ---------------- fc_w fp32 -> f16 ----------------
__global__ void k_fcw_h(const float* __restrict__ w, _Float16* __restrict__ wh) {
  size_t i = (size_t)blockIdx.x * 256 + threadIdx.x;  // one per 8 elems
  if (i >= 980000ull) return;  // 200*39200/8
  float4 v0 = ((const float4*)w)[i * 2];
  float4 v1 = ((const float4*)w)[i * 2 + 1];
  f16x8 h;
  h[0] = (_Float16)v0.x; h[1] = (_Float16)v0.y; h[2] = (_Float16)v0.z; h[3] = (_Float16)v0.w;
  h[4] = (_Float16)v1.x; h[5] = (_Float16)v1.y; h[6] = (_Float16)v1.z; h[7] = (_Float16)v1.w;
  ((f16x8*)wh)[i] = h;
}

// ---------------- gather ConvE input image + global bn stats ----------------
__global__ void k_gather_img(const float* __restrict__ x, const float* __restrict__ r,
                             const int* __restrict__ head, const int* __restrict__ rela,
                             float* __restrict__ img, float* __restrict__ bn1) {
  int b = blockIdx.x, t = threadIdx.x;
  int h = head[b], q = rela[b];
  float s1 = 0.f, s2 = 0.f;
  for (int j = t; j < 400; j += 256) {
    float v = (j < OUTC) ? x[(size_t)h * OUTC + j] : r[(size_t)q * OUTC + (j - OUTC)];
    img[(size_t)b * 400 + j] = v;
    s1 += v; s2 += v * v;
  }
  for (int off = 32; off; off >>= 1) { s1 += __shfl_down(s1, off); s2 += __shfl_down(s2, off); }
  if ((t & 63) == 0) { atomicAdd(bn1, s1); atomicAdd(bn1 + 1, s2); }
}

// ---------------- conv 7x7 valid (1->200 ch) -> f16 z1 + per-channel stats ----------------
__global__ void __launch_bounds__(256) k_conv(const float* __restrict__ img, const float* __restrict__ conv_w,
                                              const float* __restrict__ bn1, _Float16* __restrict__ z1,
                                              float* __restrict__ chsum, float* __restrict__ chss) {
  __shared__ float imgn[400];
  int b = blockIdx.x, t = threadIdx.x;
  float m = bn1[0] * (1.0f / 204800.0f);
  float var = bn1[1] * (1.0f / 204800.0f) - m * m;
  float rs = rsqrtf(var + BN_EPS);
  for (int j = t; j < 400; j += 256) imgn[j] = (img[(size_t)b * 400 + j] - m) * rs;
  __syncthreads();
  if (t < OUTC) {
    float w[49];
    #pragma unroll
    for (int i = 0; i < 49; ++i) w[i] = conv_w[t * 49 + i];
    float s1 = 0.f, s2 = 0.f;
    size_t base = (size_t)b * FCK + (size_t)t * POSN;
    for (int pos = 0; pos < POSN; ++pos) {
      int y = pos / 14, xx = pos - y * 14;
      float acc = 0.f;
      #pragma unroll
      for (int ky = 0; ky < 7; ++ky)
        #pragma unroll
        for (int kx = 0; kx < 7; ++kx)
          acc += imgn[(y + ky) * 20 + xx + kx] * w[ky * 7 + kx];
      z1[base + pos] = (_Float16)acc;
      s1 += acc; s2 += acc * acc;
    }
    atomicAdd(chsum + t, s1);
    atomicAdd(chss + t, s2);
  }
}

// ---------------- z1 = relu(bn2(z1)) in place (f16, half4 granularity; 196%4==0) ----------------
__global__ void k_bn2_relu(_Float16* __restrict__ z1, const float* __restrict__ chsum,
                           const float* __restrict__ chss) {
  size_t i = (size_t)blockIdx.x * 256 + threadIdx.x;
  if (i >= 5017600ull) return;  // 512*39200/4
  f16x4 v = ((f16x4*)z1)[i];
  int c = (int)((i * 4 % FCK) / POSN);
  const float inv = 1.0f / (512.0f * 196.0f);
  float m = chsum[c] * inv;
  float var = chss[c] * inv - m * m;
  float rs = rsqrtf(var + BN_EPS);
  #pragma unroll
  for (int e = 0; e < 4; ++e)
    v[e] = (_Float16)fmaxf(((float)v[e] - m) * rs, 0.f);
  ((f16x4*)z1)[i] = v;
}

// ---------------- fc via MFMA: z += z1h @ fcw_h.T  (K split 175x, atomic fp32 epilogue) ----------------
// A = z1h [512][39200] f16, B = fcw_h [200][39200] f16 (gemm_bt).
// Block: 4 waves, wave w: rows [by*128+w*32,+32) x all 208 cols (mask >=200).
__global__ void __launch_bounds__(256) k_fc_mfma(const _Float16* __restrict__ A,
                                                 const _Float16* __restrict__ B,
                                                 float* __restrict__ Cz) {
  int t = threadIdx.x;
  int w = t >> 6, l = t & 63;
  int lr = l & 15, kg = l >> 4;
  int m0 = blockIdx.y * 128 + w * 32;
  int ks = blockIdx.x;  // 0..174, each 7 k-steps of 32
  f32x4 acc[2][13];
  #pragma unroll
  for (int i = 0; i < 2; ++i)
    #pragma unroll
    for (int j = 0; j < 13; ++j) acc[i][j] = (f32x4){0.f, 0.f, 0.f, 0.f};

  #pragma unroll
  for (int s = 0; s < 7; ++s) {
    int k = (ks * 7 + s) * 32 + kg * 8;
    f16x8 a[2], b[13];
    #pragma unroll
    for (int i = 0; i < 2; ++i)
      a[i] = *(const f16x8*)(A + (size_t)(m0 + i * 16 + lr) * FCK + k);
    #pragma unroll
    for (int j = 0; j < 13; ++j)  // rows 200..207 read in-ws garbage; contained to cols>=200, masked on write
      b[j] = *(const f16x8*)(B + (size_t)(j * 16 + lr) * FCK + k);
    #pragma unroll
    for (int i = 0; i < 2; ++i)
      #pragma unroll
      for (int j = 0; j < 13; ++j)
        acc[i][j] = __builtin_amdgcn_mfma_f32_16x16x32_f16(a[i], b[j], acc[i][j], 0, 0, 0);
  }

  #pragma unroll
  for (int i = 0; i < 2; ++i) {
    #pragma unroll
    for (int j = 0; j < 13; ++j) {
      int col = j * 16 + lr;
      if (col < OUTC) {
        #pragma unroll
        for (int r = 0; r < 4; ++r) {
          int row = m0 + i * 16 + kg * 4 + r;
          atomicAdd(&Cz[(size_t)row * OUTC + col], acc[i][j][r]);
        }
      }
    }
  }
}

// ---------------- z = relu(bn3(z)) -> f16 z_h (per-column over 512) ----------------
__global__ void k_bn3_relu(const float* __restrict__ z, _Float16* __restrict__ zh) {
  int c = blockIdx.x, lane = threadIdx.x;  // 64 threads
  float v[8];
  float s1 = 0.f, s2 = 0.f;
  #pragma unroll
  for (int i = 0; i < 8; ++i) {
    v[i] = z[(size_t)(lane + i * 64) * OUTC + c];
    s1 += v[i]; s2 += v[i] * v[i];
  }
  for (int off = 32; off; off >>= 1) { s1 += __shfl_down(s1, off); s2 += __shfl_down(s2, off); }
  s1 = __shfl(s1, 0); s2 = __shfl(s2, 0);
  float m = s1 * (1.0f / 512.0f);
  float var = s2 * (1.0f / 512.0f) - m * m;
  float rs = rsqrtf(var + BN_EPS);
  #pragma unroll
  for (int i = 0; i < 8; ++i)
    zh[(size_t)(lane + i * 64) * OUTC + c] = (_Float16)fmaxf((v[i] - m) * rs, 0.f);
}

// ---------------- score = sigmoid(z_h @ x_h.T + b_ent) via f16 MFMA ----------------
__global__ void __launch_bounds__(256) k_score_mfma(const _Float16* __restrict__ zh,
                                                    const _Float16* __restrict__ xh,
                                                    const float* __restrict__ b_ent,
                                                    float* __restrict__ out) {
  int t = threadIdx.x;
  int w = t >> 6, l = t & 63;
  int lr = l & 15, kg = l >> 4;
  int m0 = blockIdx.y * 128 + w * 32;
  int e0 = blockIdx.x * 128;
  f32x4 acc[2][8];
  #pragma unroll
  for (int i = 0; i < 2; ++i)
    #pragma unroll
    for (int j = 0; j < 8; ++j) acc[i][j] = (f32x4){0.f, 0.f, 0.f, 0.f};

  #pragma unroll
  for (int step = 0; step < 7; ++step) {
    int k = step * 32 + kg * 8;
    bool valid = (k < 200);  // steps 0..5 always true; step 6 only kg==0
    f16x8 a[2], b[8];
    #pragma unroll
    for (int i = 0; i < 2; ++i) {
      int row = m0 + i * 16 + lr;
      a[i] = valid ? *(const f16x8*)(zh + (size_t)row * OUTC + k) : (f16x8)0;
    }
    #pragma unroll
    for (int j = 0; j < 8; ++j) {
      int col = e0 + j * 16 + lr;  // cols >= NENT read in-ws garbage; masked on write
      b[j] = valid ? *(const f16x8*)(xh + (size_t)col * OUTC + k) : (f16x8)0;
    }
    #pragma unroll
    for (int i = 0; i < 2; ++i)
      #pragma unroll
      for (int j = 0; j < 8; ++j)
        acc[i][j] = __builtin_amdgcn_mfma_f32_16x16x32_f16(a[i], b[j], acc[i][j], 0, 0, 0);
  }

  #pragma unroll
  for (int i = 0; i < 2; ++i) {
    #pragma unroll
    for (int j = 0; j < 8; ++j) {
      int e = e0 + j * 16 + lr;
      if (e < NENT) {
        float be = b_ent[e];
        #pragma unroll
        for (int r = 0; r < 4; ++r) {
          int row = m0 + i * 16 + kg * 4 + r;
          float v = acc[i][j][r] + be;
          out[(size_t)row * NENT + e] = 1.0f / (1.0f + expf(-v));
        }
      }
    }
  }
}

extern "C" void kernel_launch(void* const* d_in, const int* in_sizes, int n_in,
                              void* d_out, int out_size, void* d_ws, size_t ws_size,
                              hipStream_t stream) {
  (void)in_sizes; (void)n_in; (void)out_size; (void)ws_size;
  const float* ent_emb  = (const float*)d_in[0];
  const float* rel_emb  = (const float*)d_in[1];
  const float* in_w     = (const float*)d_in[2];
  const float* out_w    = (const float*)d_in[3];
  const float* loop_w   = (const float*)d_in[4];
  const float* w_rel    = (const float*)d_in[5];
  const float* loop_rel = (const float*)d_in[6];
  // d_in[7] gcn_bias: cancels under axis-0 BN
  const float* edge_norm= (const float*)d_in[8];
  const float* conv_w   = (const float*)d_in[9];
  const float* fc_w     = (const float*)d_in[10];
  // d_in[11] fc_b: cancels under axis-0 BN
  const float* b_ent    = (const float*)d_in[12];
  const int* esrc = (const int*)d_in[13];
  const int* edst = (const int*)d_in[14];
  const int* etyp = (const int*)d_in[15];
  const int* head = (const int*)d_in[16];
  const int* rela = (const int*)d_in[17];
  float* ws  = (float*)d_ws;
  float* out = (float*)d_out;

  // zero: acc buffers + (z + all stats)
  hipMemsetAsync(ws + OFF_ACCIN, 0, (size_t)20400000 * 4, stream);
  hipMemsetAsync(ws + OFF_Z, 0, (WS_END - OFF_Z) * 4, stream);

  k_tables<<<20, 256, 0, stream>>>(ws);
  k_rfft<<<25000, 256, 0, stream>>>(ent_emb, ws + OFF_FA, ws + OFF_DFTC, ws + OFF_DFTS, NENT);
  k_rfft<<<100, 256, 0, stream>>>(rel_emb, ws + OFF_FB, ws + OFF_DFTC, ws + OFF_DFTS, NREL);
  k_rfft<<<1, 256, 0, stream>>>(loop_rel, ws + OFF_FL, ws + OFF_DFTC, ws + OFF_DFTS, 1);
  k_wtilde<<<40, 256, 0, stream>>>(in_w, out_w, loop_w, ws);
  k_edge<<<NEDGE / 2, 256, 0, stream>>>(ws + OFF_FA, ws + OFF_FB, ws + OFF_ACCIN, ws + OFF_ACCOUT,
                                        esrc, edst, etyp, edge_norm);
  k_relmat<<<313, 256, 0, stream>>>(rel_emb, w_rel, ws + OFF_R);
  k_fused_x<<<3125, 256, 0, stream>>>(ws, ws + OFF_XBUF);
  k_colstats<<<200, 256, 0, stream>>>(ws + OFF_XBUF, ws + OFF_COLSUM, ws + OFF_COLSS);
  k_bn_tanh<<<19532, 256, 0, stream>>>(ws + OFF_XBUF, (_Float16*)(ws + OFF_XH),
                                       ws + OFF_COLSUM, ws + OFF_COLSS);
  k_fcw_h<<<3829, 256, 0, stream>>>(fc_w, (_Float16*)(ws + OFF_FCWH));
  k_gather_img<<<512, 256, 0, stream>>>(ws + OFF_XBUF, ws + OFF_R, head, rela, ws + OFF_IMG, ws + OFF_BN1);
  k_conv<<<512, 256, 0, stream>>>(ws + OFF_IMG, conv_w, ws + OFF_BN1, (_Float16*)(ws + OFF_Z1H),
                                  ws + OFF_CHSUM, ws + OFF_CHSS);
  k_bn2_relu<<<19600, 256, 0, stream>>>((_Float16*)(ws + OFF_Z1H), ws + OFF_CHSUM, ws + OFF_CHSS);
  k_fc_mfma<<<dim3(175, 4), 256, 0, stream>>>((const _Float16*)(ws + OFF_Z1H),
                                              (const _Float16*)(ws + OFF_FCWH), ws + OFF_Z);
  k_bn3_relu<<<200, 64, 0, stream>>>(ws + OFF_Z, (_Float16*)(ws + OFF_ZH));
  k_score_mfma<<<dim3(782, 4), 256, 0, stream>>>((const _Float16*)(ws + OFF_ZH),
                                                 (const _Float16*)(ws + OFF_XH),
                                                 b_ent, out);
}

// Round 4
// 1051.028 us; speedup vs baseline: 2.4145x; 1.2491x over previous
//
#include <hip/hip_runtime.h>

#define NENT  100000
#define NREL  400
#define EMB   100
#define NF    51
#define FCMP  102
#define OUTC  200
#define NEDGE 500000
#define HALFE 250000
#define BATCH 512
#define POSN  196
#define FCK   39200
#define BN_EPS 1e-5f

// ---- workspace layout (floats). Peak ~204.3 MB.
// Lifetimes: Fa dead after k_fused_x_mfma -> x_h overlays it.
//            accIn dead after k_fused_x_mfma -> z1h (f16) overlays it.
//            accOut dead after k_fused_x_mfma -> fcw_h (f16) overlays it.
//            img dead after k_conv -> z_h overlays it.
static constexpr size_t OFF_FA     = 0;          // [NENT][102] fp32
static constexpr size_t OFF_XH     = 0;          // [NENT][200] f16 overlay
static constexpr size_t OFF_ACCIN  = 10200000;   // [NENT][102]
static constexpr size_t OFF_Z1H    = 10200000;   // [512][39200] f16 overlay
static constexpr size_t OFF_ACCOUT = 20400000;   // [NENT][102]
static constexpr size_t OFF_FCWH   = 20400000;   // [200][39200] f16 overlay
static constexpr size_t OFF_XBUF   = 30600000;   // [NENT][200] fp32
static constexpr size_t OFF_FB     = 50600000;   // [NREL][102]
static constexpr size_t OFF_FL     = 50640800;   // [102] (+pad to 128)
static constexpr size_t OFF_BIGBT  = 50640928;   // [208][336] f16 = 34944 floats (zeroed)
static constexpr size_t OFF_R      = 50675872;   // [400][200]
static constexpr size_t OFF_IMG    = 50755872;   // [512][400]
static constexpr size_t OFF_ZH     = 50755872;   // [512][200] f16 overlay
static constexpr size_t OFF_DFTC   = 50960672;   // [100][51]
static constexpr size_t OFF_DFTS   = 50965772;   // [100][51]
static constexpr size_t OFF_Z      = 50970872;   // [512][200]  (memset region starts here)
static constexpr size_t OFF_COLSUM = OFF_Z + 102400;
static constexpr size_t OFF_COLSS  = OFF_COLSUM + 200;
static constexpr size_t OFF_BN1    = OFF_COLSS + 200;   // 2 (+pad to 8)
static constexpr size_t OFF_CHSUM  = OFF_BN1 + 8;
static constexpr size_t OFF_CHSS   = OFF_CHSUM + 200;
static constexpr size_t WS_END     = OFF_CHSS + 200;

typedef __attribute__((ext_vector_type(8))) _Float16 f16x8;
typedef __attribute__((ext_vector_type(4))) _Float16 f16x4;
typedef __attribute__((ext_vector_type(4))) float f32x4;

// ---------------- DFT twiddle tables ----------------
__global__ void k_tables(float* __restrict__ ws) {
  int i = blockIdx.x * 256 + threadIdx.x;
  if (i >= EMB * NF) return;
  int j = i / NF, f = i - j * NF;
  int m = (j * f) % EMB;
  float ang = (float)m * 0.06283185307179586f;  // 2*pi/100
  ws[OFF_DFTC + i] = cosf(ang);
  ws[OFF_DFTS + i] = sinf(ang);
}

// ---------------- rfft of rows (direct DFT, n=100 -> 51 complex as [re51|im51]) ----------------
__global__ void k_rfft(const float* __restrict__ src, float* __restrict__ dst,
                       const float* __restrict__ dftc, const float* __restrict__ dfts,
                       int nrows) {
  __shared__ float arow[4][EMB];
  int g = threadIdx.x >> 6;
  int lane = threadIdx.x & 63;
  int row = blockIdx.x * 4 + g;
  if (row < nrows) {
    for (int j = lane; j < EMB; j += 64) arow[g][j] = src[(size_t)row * EMB + j];
  }
  __syncthreads();
  if (row < nrows && lane < NF) {
    float re = 0.f, im = 0.f;
    for (int j = 0; j < EMB; ++j) {
      float a = arow[g][j];
      re += a * dftc[j * NF + lane];
      im -= a * dfts[j * NF + lane];
    }
    dst[(size_t)row * FCMP + lane] = re;
    dst[(size_t)row * FCMP + NF + lane] = im;
  }
}

// ---------------- fold irfft + weight + 1/3 into BigBT[208][336] f16 (transposed, zero-padded) ----
// k-index layout matches A rows: [0,102)=loop(L~), [102,204)=W~in, [204,306)=W~out; 306..335 zero.
__global__ void k_wtilde(const float* __restrict__ in_w, const float* __restrict__ out_w,
                         const float* __restrict__ loop_w, float* __restrict__ ws) {
  int id = blockIdx.x * 256 + threadIdx.x;
  if (id >= NF * OUTC) return;
  int f = id / OUTC, o = id - f * OUTC;
  const float* dftc = ws + OFF_DFTC;
  const float* dfts = ws + OFF_DFTS;
  float ci = 0, si = 0, co = 0, so = 0, cl = 0, sl = 0;
  for (int k = 0; k < EMB; ++k) {
    float c = dftc[k * NF + f], s = dfts[k * NF + f];
    float wi = in_w[k * OUTC + o], wo = out_w[k * OUTC + o], wl = loop_w[k * OUTC + o];
    ci += c * wi; si += s * wi;
    co += c * wo; so += s * wo;
    cl += c * wl; sl += s * wl;
  }
  bool ends = (f == 0) || (f == NF - 1);
  float mult = ends ? 1.0f : 2.0f;
  const float inv3n = 1.0f / (3.0f * (float)EMB);
  _Float16* bt = (_Float16*)(ws + OFF_BIGBT);
  size_t ro = (size_t)o * 336;
  bt[ro + 102 + f]      = (_Float16)(mult * ci * inv3n);
  bt[ro + 102 + NF + f] = (_Float16)(ends ? 0.f : (-2.0f * si * inv3n));
  bt[ro + 204 + f]      = (_Float16)(mult * co * inv3n);
  bt[ro + 204 + NF + f] = (_Float16)(ends ? 0.f : (-2.0f * so * inv3n));
  float wlre = mult * cl * inv3n;
  float wlim = ends ? 0.f : (-2.0f * sl * inv3n);
  float flr = ws[OFF_FL + f], fli = ws[OFF_FL + NF + f];
  bt[ro + f]      = (_Float16)(flr * wlre + fli * wlim);
  bt[ro + NF + f] = (_Float16)(fli * wlre - flr * wlim);
}

// ---------------- per-edge: accF[dst,half] += norm * conj(Fa[src]) * Fb[type] ----------------
__global__ void k_edge(const float* __restrict__ fa_t, const float* __restrict__ fb_t,
                       float* __restrict__ accIn, float* __restrict__ accOut,
                       const int* __restrict__ esrc, const int* __restrict__ edst,
                       const int* __restrict__ etyp, const float* __restrict__ enorm) {
  int sub = threadIdx.x >> 7;
  int l = threadIdx.x & 127;
  int e = blockIdx.x * 2 + sub;
  if (e >= NEDGE || l >= FCMP) return;
  int s = esrc[e], d = edst[e], ty = etyp[e];
  float nor = enorm[e];
  int f = (l < NF) ? l : (l - NF);
  const float* fa = fa_t + (size_t)s * FCMP;
  const float* fb = fb_t + (size_t)ty * FCMP;
  float far = fa[f], fai = fa[NF + f], fbr = fb[f], fbi = fb[NF + f];
  float v = (l < NF) ? (far * fbr + fai * fbi) : (far * fbi - fai * fbr);
  float* acc = (e < HALFE) ? accIn : accOut;
  atomicAdd(acc + (size_t)d * FCMP + l, v * nor);
}

// ---------------- r = rel_emb @ w_rel ----------------
__global__ void k_relmat(const float* __restrict__ rel_emb, const float* __restrict__ w_rel,
                         float* __restrict__ r) {
  int id = blockIdx.x * 256 + threadIdx.x;
  if (id >= NREL * OUTC) return;
  int rr = id / OUTC, o = id - rr * OUTC;
  float acc = 0.f;
  for (int k = 0; k < EMB; ++k) acc += rel_emb[rr * EMB + k] * w_rel[k * OUTC + o];
  r[id] = acc;
}

// ---------------- x_pre = [Fa | accIn | accOut] @ BigBT.T via f16 MFMA (f32 loads, cvt in-reg) ----
// A rows: 3 segments (Fa, accIn, accOut), each [NENT][102] f32, pitch 102.
// Block: 4 waves; wave w: rows [bx*128 + w*32, +32) x 208 cols (mask >=200 on write).
// Per segment: 4 k-steps of 32; step 3 masks k>=102 to zero after cvt.
__global__ void __launch_bounds__(256) k_fused_x_mfma(const float* __restrict__ ws,
                                                      float* __restrict__ xbuf) {
  int t = threadIdx.x;
  int w = t >> 6, l = t & 63;
  int lr = l & 15, kg = l >> 4;
  size_t row0 = (size_t)blockIdx.x * 128 + w * 32;
  const _Float16* BT = (const _Float16*)(ws + OFF_BIGBT);
  const float* segp[3] = {ws + OFF_FA, ws + OFF_ACCIN, ws + OFF_ACCOUT};
  f32x4 acc[2][13];
  #pragma unroll
  for (int i = 0; i < 2; ++i)
    #pragma unroll
    for (int j = 0; j < 13; ++j) acc[i][j] = (f32x4){0.f, 0.f, 0.f, 0.f};

  #pragma unroll
  for (int seg = 0; seg < 3; ++seg) {
    const float* P = segp[seg];
    #pragma unroll
    for (int st = 0; st < 4; ++st) {
      int koff = st * 32 + kg * 8;
      f16x8 a[2];
      #pragma unroll
      for (int i = 0; i < 2; ++i) {
        const float* p = P + (row0 + i * 16 + lr) * FCMP + koff;
        float4 p0 = *(const float4*)p;
        float4 p1 = *(const float4*)(p + 4);
        f16x8 h;
        if (st < 3) {
          h[0] = (_Float16)p0.x; h[1] = (_Float16)p0.y; h[2] = (_Float16)p0.z; h[3] = (_Float16)p0.w;
          h[4] = (_Float16)p1.x; h[5] = (_Float16)p1.y; h[6] = (_Float16)p1.z; h[7] = (_Float16)p1.w;
        } else {  // koff = 96 + kg*8; valid elements: koff+e < 102
          float pv[8] = {p0.x, p0.y, p0.z, p0.w, p1.x, p1.y, p1.z, p1.w};
          #pragma unroll
          for (int e = 0; e < 8; ++e)
            h[e] = (koff + e < FCMP) ? (_Float16)pv[e] : (_Float16)0.f;
        }
        a[i] = h;
      }
      f16x8 b[13];
      #pragma unroll
      for (int j = 0; j < 13; ++j)
        b[j] = *(const f16x8*)(BT + (size_t)(j * 16 + lr) * 336 + seg * FCMP + koff);
      #pragma unroll
      for (int i = 0; i < 2; ++i)
        #pragma unroll
        for (int j = 0; j < 13; ++j)
          acc[i][j] = __builtin_amdgcn_mfma_f32_16x16x32_f16(a[i], b[j], acc[i][j], 0, 0, 0);
    }
  }

  #pragma unroll
  for (int i = 0; i < 2; ++i) {
    #pragma unroll
    for (int j = 0; j < 13; ++j) {
      int col = j * 16 + lr;
      if (col < OUTC) {
        #pragma unroll
        for (int r = 0; r < 4; ++r) {
          size_t row = row0 + i * 16 + kg * 4 + r;
          if (row < NENT) xbuf[row * OUTC + col] = acc[i][j][r];
        }
      }
    }
  }
}

// ---------------- column stats of xbuf ----------------
__global__ void k_colstats(const float* __restrict__ x, float* __restrict__ colsum,
                           float* __restrict__ colss) {
  int t = threadIdx.x;
  if (t >= OUTC) return;
  size_t r0 = (size_t)blockIdx.x * 500;
  float s1 = 0.f, s2 = 0.f;
  for (int i = 0; i < 500; ++i) {
    float v = x[(r0 + i) * OUTC + t];
    s1 += v; s2 += v * v;
  }
  atomicAdd(colsum + t, s1);
  atomicAdd(colss + t, s2);
}

// ---------------- x = tanh(bn0(x_pre)) in place + f16 copy ----------------
__global__ void k_bn_tanh(float* __restrict__ x, _Float16* __restrict__ xh,
                          const float* __restrict__ colsum, const float* __restrict__ colss) {
  size_t i = (size_t)blockIdx.x * 256 + threadIdx.x;
  if (i >= 5000000ull) return;  // NENT*OUTC/4
  float4 v = ((float4*)x)[i];
  int c = (int)((i * 4) % OUTC);
  const float inv = 1.0f / (float)NENT;
  float m, q, rs;
  m = colsum[c] * inv;     q = colss[c] * inv - m * m;     rs = rsqrtf(q + BN_EPS); v.x = tanhf((v.x - m) * rs);
  m = colsum[c + 1] * inv; q = colss[c + 1] * inv - m * m; rs = rsqrtf(q + BN_EPS); v.y = tanhf((v.y - m) * rs);
  m = colsum[c + 2] * inv; q = colss[c + 2] * inv - m * m; rs = rsqrtf(q + BN_EPS); v.z = tanhf((v.z - m) * rs);
  m = colsum[c + 3] * inv; q = colss[c + 3] * inv - m * m; rs = rsqrtf(q + BN_EPS); v.w = tanhf((v.w - m) * rs);
  ((float4*)x)[i] = v;
  f16x4 h;
  h[0] = (_Float16)v.x; h[1] = (_Float16)v.y; h[2] = (_Float16)v.z; h[3] = (_Float16)v.w;
  *(f16x4*)(xh + i * 4) = h;
}

// ---------------- fc_w fp32 -> f16 ----------------
__global__ void k_fcw_h(const float* __restrict__ w, _Float16* __restrict__ wh) {
  size_t i = (size_t)blockIdx.x * 256 + threadIdx.x;  // one per 8 elems
  if (i >= 980000ull) return;  // 200*39200/8
  float4 v0 = ((const float4*)w)[i * 2];
  float4 v1 = ((const float4*)w)[i * 2 + 1];
  f16x8 h;
  h[0] = (_Float16)v0.x; h[1] = (_Float16)v0.y; h[2] = (_Float16)v0.z; h[3] = (_Float16)v0.w;
  h[4] = (_Float16)v1.x; h[5] = (_Float16)v1.y; h[6] = (_Float16)v1.z; h[7] = (_Float16)v1.w;
  ((f16x8*)wh)[i] = h;
}

// ---------------- gather ConvE input image + global bn stats ----------------
__global__ void k_gather_img(const float* __restrict__ x, const float* __restrict__ r,
                             const int* __restrict__ head, const int* __restrict__ rela,
                             float* __restrict__ img, float* __restrict__ bn1) {
  int b = blockIdx.x, t = threadIdx.x;
  int h = head[b], q = rela[b];
  float s1 = 0.f, s2 = 0.f;
  for (int j = t; j < 400; j += 256) {
    float v = (j < OUTC) ? x[(size_t)h * OUTC + j] : r[(size_t)q * OUTC + (j - OUTC)];
    img[(size_t)b * 400 + j] = v;
    s1 += v; s2 += v * v;
  }
  for (int off = 32; off; off >>= 1) { s1 += __shfl_down(s1, off); s2 += __shfl_down(s2, off); }
  if ((t & 63) == 0) { atomicAdd(bn1, s1); atomicAdd(bn1 + 1, s2); }
}

// ---------------- conv 7x7 valid (1->200 ch) -> f16 z1 + per-channel stats ----------------
__global__ void __launch_bounds__(256) k_conv(const float* __restrict__ img, const float* __restrict__ conv_w,
                                              const float* __restrict__ bn1, _Float16* __restrict__ z1,
                                              float* __restrict__ chsum, float* __restrict__ chss) {
  __shared__ float imgn[400];
  int b = blockIdx.x, t = threadIdx.x;
  float m = bn1[0] * (1.0f / 204800.0f);
  float var = bn1[1] * (1.0f / 204800.0f) - m * m;
  float rs = rsqrtf(var + BN_EPS);
  for (int j = t; j < 400; j += 256) imgn[j] = (img[(size_t)b * 400 + j] - m) * rs;
  __syncthreads();
  if (t < OUTC) {
    float w[49];
    #pragma unroll
    for (int i = 0; i < 49; ++i) w[i] = conv_w[t * 49 + i];
    float s1 = 0.f, s2 = 0.f;
    size_t base = (size_t)b * FCK + (size_t)t * POSN;
    for (int pos = 0; pos < POSN; ++pos) {
      int y = pos / 14, xx = pos - y * 14;
      float acc = 0.f;
      #pragma unroll
      for (int ky = 0; ky < 7; ++ky)
        #pragma unroll
        for (int kx = 0; kx < 7; ++kx)
          acc += imgn[(y + ky) * 20 + xx + kx] * w[ky * 7 + kx];
      z1[base + pos] = (_Float16)acc;
      s1 += acc; s2 += acc * acc;
    }
    atomicAdd(chsum + t, s1);
    atomicAdd(chss + t, s2);
  }
}

// ---------------- z1 = relu(bn2(z1)) in place (f16) ----------------
__global__ void k_bn2_relu(_Float16* __restrict__ z1, const float* __restrict__ chsum,
                           const float* __restrict__ chss) {
  size_t i = (size_t)blockIdx.x * 256 + threadIdx.x;
  if (i >= 5017600ull) return;  // 512*39200/4
  f16x4 v = ((f16x4*)z1)[i];
  int c = (int)((i * 4 % FCK) / POSN);
  const float inv = 1.0f / (512.0f * 196.0f);
  float m = chsum[c] * inv;
  float var = chss[c] * inv - m * m;
  float rs = rsqrtf(var + BN_EPS);
  #pragma unroll
  for (int e = 0; e < 4; ++e)
    v[e] = (_Float16)fmaxf(((float)v[e] - m) * rs, 0.f);
  ((f16x4*)z1)[i] = v;
}

// ---------------- fc via MFMA: z += z1h @ fcw_h.T  (K split 175x, atomic fp32 epilogue) ----------------
__global__ void __launch_bounds__(256) k_fc_mfma(const _Float16* __restrict__ A,
                                                 const _Float16* __restrict__ B,
                                                 float* __restrict__ Cz) {
  int t = threadIdx.x;
  int w = t >> 6, l = t & 63;
  int lr = l & 15, kg = l >> 4;
  int m0 = blockIdx.y * 128 + w * 32;
  int ks = blockIdx.x;  // 0..174, each 7 k-steps of 32
  f32x4 acc[2][13];
  #pragma unroll
  for (int i = 0; i < 2; ++i)
    #pragma unroll
    for (int j = 0; j < 13; ++j) acc[i][j] = (f32x4){0.f, 0.f, 0.f, 0.f};

  #pragma unroll
  for (int s = 0; s < 7; ++s) {
    int k = (ks * 7 + s) * 32 + kg * 8;
    f16x8 a[2], b[13];
    #pragma unroll
    for (int i = 0; i < 2; ++i)
      a[i] = *(const f16x8*)(A + (size_t)(m0 + i * 16 + lr) * FCK + k);
    #pragma unroll
    for (int j = 0; j < 13; ++j)  // rows 200..207 read in-ws garbage; masked on write
      b[j] = *(const f16x8*)(B + (size_t)(j * 16 + lr) * FCK + k);
    #pragma unroll
    for (int i = 0; i < 2; ++i)
      #pragma unroll
      for (int j = 0; j < 13; ++j)
        acc[i][j] = __builtin_amdgcn_mfma_f32_16x16x32_f16(a[i], b[j], acc[i][j], 0, 0, 0);
  }

  #pragma unroll
  for (int i = 0; i < 2; ++i) {
    #pragma unroll
    for (int j = 0; j < 13; ++j) {
      int col = j * 16 + lr;
      if (col < OUTC) {
        #pragma unroll
        for (int r = 0; r < 4; ++r) {
          int row = m0 + i * 16 + kg * 4 + r;
          atomicAdd(&Cz[(size_t)row * OUTC + col], acc[i][j][r]);
        }
      }
    }
  }
}

// ---------------- z = relu(bn3(z)) -> f16 z_h (per-column over 512) ----------------
__global__ void k_bn3_relu(const float* __restrict__ z, _Float16* __restrict__ zh) {
  int c = blockIdx.x, lane = threadIdx.x;  // 64 threads
  float v[8];
  float s1 = 0.f, s2 = 0.f;
  #pragma unroll
  for (int i = 0; i < 8; ++i) {
    v[i] = z[(size_t)(lane + i * 64) * OUTC + c];
    s1 += v[i]; s2 += v[i] * v[i];
  }
  for (int off = 32; off; off >>= 1) { s1 += __shfl_down(s1, off); s2 += __shfl_down(s2, off); }
  s1 = __shfl(s1, 0); s2 = __shfl(s2, 0);
  float m = s1 * (1.0f / 512.0f);
  float var = s2 * (1.0f / 512.0f) - m * m;
  float rs = rsqrtf(var + BN_EPS);
  #pragma unroll
  for (int i = 0; i < 8; ++i)
    zh[(size_t)(lane + i * 64) * OUTC + c] = (_Float16)fmaxf((v[i] - m) * rs, 0.f);
}

// ---------------- score = sigmoid(z_h @ x_h.T + b_ent) via f16 MFMA ----------------
__global__ void __launch_bounds__(256) k_score_mfma(const _Float16* __restrict__ zh,
                                                    const _Float16* __restrict__ xh,
                                                    const float* __restrict__ b_ent,
                                                    float* __restrict__ out) {
  int t = threadIdx.x;
  int w = t >> 6, l = t & 63;
  int lr = l & 15, kg = l >> 4;
  int m0 = blockIdx.y * 128 + w * 32;
  int e0 = blockIdx.x * 128;
  f32x4 acc[2][8];
  #pragma unroll
  for (int i = 0; i < 2; ++i)
    #pragma unroll
    for (int j = 0; j < 8; ++j) acc[i][j] = (f32x4){0.f, 0.f, 0.f, 0.f};

  #pragma unroll
  for (int step = 0; step < 7; ++step) {
    int k = step * 32 + kg * 8;
    bool valid = (k < 200);  // steps 0..5 always true; step 6 only kg==0
    f16x8 a[2], b[8];
    #pragma unroll
    for (int i = 0; i < 2; ++i) {
      int row = m0 + i * 16 + lr;
      a[i] = valid ? *(const f16x8*)(zh + (size_t)row * OUTC + k) : (f16x8)0;
    }
    #pragma unroll
    for (int j = 0; j < 8; ++j) {
      int col = e0 + j * 16 + lr;  // cols >= NENT read in-ws garbage; masked on write
      b[j] = valid ? *(const f16x8*)(xh + (size_t)col * OUTC + k) : (f16x8)0;
    }
    #pragma unroll
    for (int i = 0; i < 2; ++i)
      #pragma unroll
      for (int j = 0; j < 8; ++j)
        acc[i][j] = __builtin_amdgcn_mfma_f32_16x16x32_f16(a[i], b[j], acc[i][j], 0, 0, 0);
  }

  #pragma unroll
  for (int i = 0; i < 2; ++i) {
    #pragma unroll
    for (int j = 0; j < 8; ++j) {
      int e = e0 + j * 16 + lr;
      if (e < NENT) {
        float be = b_ent[e];
        #pragma unroll
        for (int r = 0; r < 4; ++r) {
          int row = m0 + i * 16 + kg * 4 + r;
          float v = acc[i][j][r] + be;
          out[(size_t)row * NENT + e] = 1.0f / (1.0f + expf(-v));
        }
      }
    }
  }
}

extern "C" void kernel_launch(void* const* d_in, const int* in_sizes, int n_in,
                              void* d_out, int out_size, void* d_ws, size_t ws_size,
                              hipStream_t stream) {
  (void)in_sizes; (void)n_in; (void)out_size; (void)ws_size;
  const float* ent_emb  = (const float*)d_in[0];
  const float* rel_emb  = (const float*)d_in[1];
  const float* in_w     = (const float*)d_in[2];
  const float* out_w    = (const float*)d_in[3];
  const float* loop_w   = (const float*)d_in[4];
  const float* w_rel    = (const float*)d_in[5];
  const float* loop_rel = (const float*)d_in[6];
  // d_in[7] gcn_bias: cancels under axis-0 BN
  const float* edge_norm= (const float*)d_in[8];
  const float* conv_w   = (const float*)d_in[9];
  const float* fc_w     = (const float*)d_in[10];
  // d_in[11] fc_b: cancels under axis-0 BN
  const float* b_ent    = (const float*)d_in[12];
  const int* esrc = (const int*)d_in[13];
  const int* edst = (const int*)d_in[14];
  const int* etyp = (const int*)d_in[15];
  const int* head = (const int*)d_in[16];
  const int* rela = (const int*)d_in[17];
  float* ws  = (float*)d_ws;
  float* out = (float*)d_out;

  // zero: acc buffers, BigBT (f16 pad region), z + stats
  hipMemsetAsync(ws + OFF_ACCIN, 0, (size_t)20400000 * 4, stream);
  hipMemsetAsync(ws + OFF_BIGBT, 0, (size_t)34944 * 4, stream);
  hipMemsetAsync(ws + OFF_Z, 0, (WS_END - OFF_Z) * 4, stream);

  k_tables<<<20, 256, 0, stream>>>(ws);
  k_rfft<<<25000, 256, 0, stream>>>(ent_emb, ws + OFF_FA, ws + OFF_DFTC, ws + OFF_DFTS, NENT);
  k_rfft<<<100, 256, 0, stream>>>(rel_emb, ws + OFF_FB, ws + OFF_DFTC, ws + OFF_DFTS, NREL);
  k_rfft<<<1, 256, 0, stream>>>(loop_rel, ws + OFF_FL, ws + OFF_DFTC, ws + OFF_DFTS, 1);
  k_wtilde<<<40, 256, 0, stream>>>(in_w, out_w, loop_w, ws);
  k_edge<<<NEDGE / 2, 256, 0, stream>>>(ws + OFF_FA, ws + OFF_FB, ws + OFF_ACCIN, ws + OFF_ACCOUT,
                                        esrc, edst, etyp, edge_norm);
  k_relmat<<<313, 256, 0, stream>>>(rel_emb, w_rel, ws + OFF_R);
  k_fused_x_mfma<<<782, 256, 0, stream>>>(ws, ws + OFF_XBUF);
  k_colstats<<<200, 256, 0, stream>>>(ws + OFF_XBUF, ws + OFF_COLSUM, ws + OFF_COLSS);
  k_bn_tanh<<<19532, 256, 0, stream>>>(ws + OFF_XBUF, (_Float16*)(ws + OFF_XH),
                                       ws + OFF_COLSUM, ws + OFF_COLSS);
  k_fcw_h<<<3829, 256, 0, stream>>>(fc_w, (_Float16*)(ws + OFF_FCWH));
  k_gather_img<<<512, 256, 0, stream>>>(ws + OFF_XBUF, ws + OFF_R, head, rela, ws + OFF_IMG, ws + OFF_BN1);
  k_conv<<<512, 256, 0, stream>>>(ws + OFF_IMG, conv_w, ws + OFF_BN1, (_Float16*)(ws + OFF_Z1H),
                                  ws + OFF_CHSUM, ws + OFF_CHSS);
  k_bn2_relu<<<19600, 256, 0, stream>>>((_Float16*)(ws + OFF_Z1H), ws + OFF_CHSUM, ws + OFF_CHSS);
  k_fc_mfma<<<dim3(175, 4), 256, 0, stream>>>((const _Float16*)(ws + OFF_Z1H),
                                              (const _Float16*)(ws + OFF_FCWH), ws + OFF_Z);
  k_bn3_relu<<<200, 64, 0, stream>>>(ws + OFF_Z, (_Float16*)(ws + OFF_ZH));
  k_score_mfma<<<dim3(782, 4), 256, 0, stream>>>((const _Float16*)(ws + OFF_ZH),
                                                 (const _Float16*)(ws + OFF_XH),
                                                 b_ent, out);
}